// Round 1
// baseline (396.262 us; speedup 1.0000x reference)
//
#include <hip/hip_runtime.h>

#define D 1024
#define T 2048
#define BATCH 2
#define NR 4096
#define NH 16
#define HID 512

typedef unsigned short u16;
typedef unsigned int u32;
typedef float f32x4 __attribute__((ext_vector_type(4)));
typedef __bf16 bf16x8 __attribute__((ext_vector_type(8)));

__device__ __forceinline__ u16 f2bf(float f) {
    union { float f; u32 u; } v; v.f = f;
    u32 r = v.u + 0x7fffu + ((v.u >> 16) & 1u);
    return (u16)(r >> 16);
}

// ---------------- quantile MLP stage 1: partial sums + importance scale ----------------
__global__ __launch_bounds__(256) void k_mlp1(const float* __restrict__ qtl,
        const float* __restrict__ w1q, const float* __restrict__ b1q, const float* __restrict__ w2q,
        const float* __restrict__ w1k, const float* __restrict__ b1k, const float* __restrict__ w2k,
        const float* __restrict__ w1v, const float* __restrict__ b1v, const float* __restrict__ w2v,
        const float* __restrict__ qimp, float* __restrict__ part, float* __restrict__ scl)
{
    int dc = blockIdx.x;       // 0..3  (256 d each)
    int jc = blockIdx.y;       // 0..3  (128 j each)
    int wb = blockIdx.z;       // 0..5 : which*2 + b
    int which = wb >> 1, b = wb & 1;
    const float *w1, *b1, *w2;
    if (which == 0)      { w1 = w1q; b1 = b1q; w2 = w2q; }
    else if (which == 1) { w1 = w1k; b1 = b1k; w2 = w2k; }
    else                 { w1 = w1v; b1 = b1v; w2 = w2v; }
    int tid = threadIdx.x;
    __shared__ float h[128];
    if (tid < 128) {
        int j = jc * 128 + tid;
        h[tid] = fmaxf(qtl[b] * w1[j] + b1[j], 0.0f);
    }
    __syncthreads();
    int d = dc * 256 + tid;
    float acc = 0.0f;
    for (int j = 0; j < 128; ++j) acc += h[j] * w2[(size_t)(jc * 128 + j) * D + d];
    part[((size_t)wb * 4 + jc) * D + d] = acc;
    if (dc == 0 && jc == 0 && wb == 0 && tid < BATCH) {
        float mx = qimp[0];
        for (int i = 1; i < 100; ++i) mx = fmaxf(mx, qimp[i]);
        float q = qtl[tid];
        int idx = (int)(q * 100.0f);
        idx = idx < 0 ? 0 : (idx > 99 ? 99 : idx);
        float imp = qimp[idx];
        if (mx > 0.0f) imp /= mx;
        scl[tid] = 1.0f + imp;
    }
}

// ---------------- quantile MLP stage 2: reduce partials + bias ----------------
__global__ __launch_bounds__(256) void k_mlp2(const float* __restrict__ part,
        const float* __restrict__ b2q, const float* __restrict__ b2k, const float* __restrict__ b2v,
        float* __restrict__ embeds)
{
    int dc = blockIdx.x;   // 0..3
    int wb = blockIdx.y;   // 0..5
    int which = wb >> 1;
    const float* b2 = which == 0 ? b2q : which == 1 ? b2k : b2v;
    int d = dc * 256 + threadIdx.x;
    float acc = b2[d];
    #pragma unroll
    for (int jc = 0; jc < 4; ++jc) acc += part[((size_t)wb * 4 + jc) * D + d];
    embeds[(size_t)wb * D + d] = acc;   // [which][b][d]
}

// ---------------- x + sinusoidal PE; fp32 residual copy + bf16 copy ----------------
__global__ __launch_bounds__(256) void k_pe(const float* __restrict__ x,
                                            float* __restrict__ xpe, u16* __restrict__ xpeb)
{
    int idx = (blockIdx.x * 256 + threadIdx.x) * 4;
    int d = idx & (D - 1);
    int t = (idx >> 10) & (T - 1);
    const float KL = -0.0089944731946f;  // -ln(10000)/1024
    float ft = (float)t;
    float dv0 = __expf((float)d * KL);
    float dv1 = __expf((float)(d + 2) * KL);
    float a0 = ft * dv0, a1 = ft * dv1;
    float4 xv = *reinterpret_cast<const float4*>(x + idx);
    float4 r;
    r.x = xv.x + __sinf(a0);
    r.y = xv.y + __cosf(a0);
    r.z = xv.z + __sinf(a1);
    r.w = xv.w + __cosf(a1);
    *reinterpret_cast<float4*>(xpe + idx) = r;
    ushort4 o;
    o.x = f2bf(r.x); o.y = f2bf(r.y); o.z = f2bf(r.z); o.w = f2bf(r.w);
    *reinterpret_cast<ushort4*>(xpeb + idx) = o;
}

// ---------------- weight transpose + bf16 convert: Wt[n][k] = bf16(W[k][n]) ----------------
__global__ __launch_bounds__(256) void k_wconv(const float* __restrict__ Wq, const float* __restrict__ Wk,
                                               const float* __restrict__ Wv, const float* __restrict__ Wo,
                                               u16* __restrict__ Wt)
{
    __shared__ float tile[64][65];
    int z = blockIdx.z;
    const float* W = z == 0 ? Wq : z == 1 ? Wk : z == 2 ? Wv : Wo;
    u16* out = Wt + (size_t)z * D * D;
    int n0 = blockIdx.x * 64, k0 = blockIdx.y * 64;
    int r = threadIdx.x >> 4;
    int c4 = (threadIdx.x & 15) * 4;
    #pragma unroll
    for (int rr = 0; rr < 64; rr += 16) {
        float4 v = *reinterpret_cast<const float4*>(W + (size_t)(k0 + r + rr) * D + n0 + c4);
        tile[r + rr][c4 + 0] = v.x; tile[r + rr][c4 + 1] = v.y;
        tile[r + rr][c4 + 2] = v.z; tile[r + rr][c4 + 3] = v.w;
    }
    __syncthreads();
    #pragma unroll
    for (int rr = 0; rr < 64; rr += 16) {
        ushort4 o;
        o.x = f2bf(tile[c4 + 0][r + rr]);
        o.y = f2bf(tile[c4 + 1][r + rr]);
        o.z = f2bf(tile[c4 + 2][r + rr]);
        o.w = f2bf(tile[c4 + 3][r + rr]);
        *reinterpret_cast<ushort4*>(out + (size_t)(n0 + r + rr) * D + k0 + c4) = o;
    }
}

// ---------------- shared 128x128 bf16 MFMA GEMM core (K=1024, BK=64) ----------------
// A[m][k] row-major bf16, B = Wt[n][k] row-major bf16 (i.e. B^T layout).
__device__ __forceinline__ void gemm128(const u16* __restrict__ Ag, const u16* __restrict__ Bg,
                                        int m0, int n0, f32x4 acc[4][4])
{
    __shared__ u16 As[128 * 64];
    __shared__ u16 Bs[128 * 64];
    const int tid = threadIdx.x;
    const int lane = tid & 63, wave = tid >> 6;
    const int wr = wave >> 1, wc = wave & 1;
    #pragma unroll
    for (int i = 0; i < 4; ++i)
        #pragma unroll
        for (int j = 0; j < 4; ++j)
            #pragma unroll
            for (int e = 0; e < 4; ++e) acc[i][j][e] = 0.0f;

    int4 ar[4], br[4];
    #pragma unroll
    for (int c = 0; c < 4; ++c) {
        int ci = c * 256 + tid;
        int row = ci >> 3, sl = ci & 7;
        ar[c] = *reinterpret_cast<const int4*>(Ag + (size_t)(m0 + row) * D + sl * 8);
        br[c] = *reinterpret_cast<const int4*>(Bg + (size_t)(n0 + row) * D + sl * 8);
    }
    for (int kt = 0; kt < 16; ++kt) {
        __syncthreads();
        #pragma unroll
        for (int c = 0; c < 4; ++c) {
            int ci = c * 256 + tid;
            int row = ci >> 3, sp = (ci & 7) ^ (row & 7);
            *reinterpret_cast<int4*>((char*)As + row * 128 + sp * 16) = ar[c];
            *reinterpret_cast<int4*>((char*)Bs + row * 128 + sp * 16) = br[c];
        }
        __syncthreads();
        if (kt < 15) {
            int k0 = (kt + 1) * 64;
            #pragma unroll
            for (int c = 0; c < 4; ++c) {
                int ci = c * 256 + tid;
                int row = ci >> 3, sl = ci & 7;
                ar[c] = *reinterpret_cast<const int4*>(Ag + (size_t)(m0 + row) * D + k0 + sl * 8);
                br[c] = *reinterpret_cast<const int4*>(Bg + (size_t)(n0 + row) * D + k0 + sl * 8);
            }
        }
        #pragma unroll
        for (int ks = 0; ks < 2; ++ks) {
            bf16x8 af[4], bfr[4];
            #pragma unroll
            for (int i = 0; i < 4; ++i) {
                int ra = wr * 64 + i * 16 + (lane & 15);
                int sa = ((ks * 4 + (lane >> 4)) ^ (ra & 7));
                af[i] = *reinterpret_cast<const bf16x8*>((const char*)As + ra * 128 + sa * 16);
                int rb = wc * 64 + i * 16 + (lane & 15);
                int sb = ((ks * 4 + (lane >> 4)) ^ (rb & 7));
                bfr[i] = *reinterpret_cast<const bf16x8*>((const char*)Bs + rb * 128 + sb * 16);
            }
            #pragma unroll
            for (int i = 0; i < 4; ++i)
                #pragma unroll
                for (int j = 0; j < 4; ++j)
                    acc[i][j] = __builtin_amdgcn_mfma_f32_16x16x32_bf16(af[i], bfr[j], acc[i][j], 0, 0, 0);
        }
    }
}

// ---------------- Q/K/V projections ----------------
__global__ __launch_bounds__(256, 2)
void k_qkv(const u16* __restrict__ A, const u16* __restrict__ Wt,
           const float* __restrict__ bq, const float* __restrict__ bk, const float* __restrict__ bv,
           const float* __restrict__ embeds,
           u16* __restrict__ Qo, u16* __restrict__ Ko, u16* __restrict__ Vt)
{
    int which = blockIdx.z;
    const u16* Bg = Wt + (size_t)which * D * D;
    const float* bias = which == 0 ? bq : which == 1 ? bk : bv;
    const float* emb = embeds + which * (BATCH * D);
    int m0 = blockIdx.x * 128, n0 = blockIdx.y * 128;
    f32x4 acc[4][4];
    gemm128(A, Bg, m0, n0, acc);
    int lane = threadIdx.x & 63, wave = threadIdx.x >> 6;
    int wr = wave >> 1, wc = wave & 1;
    int rowbase = m0 + wr * 64 + ((lane >> 4) << 2);
    int colbase = n0 + wc * 64 + (lane & 15);
    if (which < 2) {
        u16* Out = which == 0 ? Qo : Ko;
        #pragma unroll
        for (int j = 0; j < 4; ++j) {
            int c = colbase + j * 16;
            float add0 = bias[c] + emb[c];
            float add1 = bias[c] + emb[D + c];
            #pragma unroll
            for (int i = 0; i < 4; ++i) {
                int rb = rowbase + i * 16;
                #pragma unroll
                for (int jj = 0; jj < 4; ++jj) {
                    int r = rb + jj;
                    Out[(size_t)r * D + c] = f2bf(acc[i][j][jj] + ((r >> 11) ? add1 : add0));
                }
            }
        }
    } else {
        // V stored transposed per-head: Vt[((b*NH + h)*64 + cc)][t]
        #pragma unroll
        for (int j = 0; j < 4; ++j) {
            int c = colbase + j * 16;
            int hh = c >> 6, cc = c & 63;
            float add0 = bias[c] + emb[c];
            float add1 = bias[c] + emb[D + c];
            #pragma unroll
            for (int i = 0; i < 4; ++i) {
                int rb = rowbase + i * 16;
                int bb = rb >> 11;
                int t = rb & (T - 1);
                float add = bb ? add1 : add0;
                ushort4 o;
                o.x = f2bf(acc[i][j][0] + add);
                o.y = f2bf(acc[i][j][1] + add);
                o.z = f2bf(acc[i][j][2] + add);
                o.w = f2bf(acc[i][j][3] + add);
                *reinterpret_cast<ushort4*>(Vt + ((size_t)((bb * NH + hh) * 64 + cc)) * T + t) = o;
            }
        }
    }
}

// ---------------- flash attention: 64 q-rows/block, KV tiles of 64 ----------------
__global__ __launch_bounds__(256, 3)
void k_attn(const u16* __restrict__ Q, const u16* __restrict__ K, const u16* __restrict__ Vt,
            const float* __restrict__ scalep, u16* __restrict__ AO)
{
    __shared__ u16 Ks[64 * 64];
    __shared__ u16 Vs[64 * 64];
    __shared__ u16 Ps[64][72];
    int bh = blockIdx.y;
    int b = bh >> 4, hh = bh & 15;
    int q0 = blockIdx.x * 64;
    int tid = threadIdx.x;
    int lane = tid & 63, wave = tid >> 6;
    float sc = scalep[b] * 0.125f;   // scale / sqrt(64)

    bf16x8 qf[2];
    {
        size_t off = (size_t)(b * T + q0 + wave * 16 + (lane & 15)) * D + hh * 64 + ((lane >> 4) << 3);
        qf[0] = *reinterpret_cast<const bf16x8*>(Q + off);
        qf[1] = *reinterpret_cast<const bf16x8*>(Q + off + 32);
    }

    f32x4 o[4];
    float m_run[4], l_run[4];
    #pragma unroll
    for (int j = 0; j < 4; ++j)
        #pragma unroll
        for (int e = 0; e < 4; ++e) o[j][e] = 0.0f;
    #pragma unroll
    for (int jj = 0; jj < 4; ++jj) { m_run[jj] = -1e30f; l_run[jj] = 0.0f; }

    int4 kr[2], vr[2];
    #pragma unroll
    for (int c = 0; c < 2; ++c) {
        int ci = c * 256 + tid;
        int row = ci >> 3, sl = ci & 7;
        kr[c] = *reinterpret_cast<const int4*>(K + (size_t)(b * T + row) * D + hh * 64 + sl * 8);
        vr[c] = *reinterpret_cast<const int4*>(Vt + (size_t)(bh * 64 + row) * T + sl * 8);
    }

    for (int kt = 0; kt < 32; ++kt) {
        __syncthreads();
        #pragma unroll
        for (int c = 0; c < 2; ++c) {
            int ci = c * 256 + tid;
            int row = ci >> 3, sp = (ci & 7) ^ (row & 7);
            *reinterpret_cast<int4*>((char*)Ks + row * 128 + sp * 16) = kr[c];
            *reinterpret_cast<int4*>((char*)Vs + row * 128 + sp * 16) = vr[c];
        }
        __syncthreads();
        if (kt < 31) {
            int t0 = (kt + 1) * 64;
            #pragma unroll
            for (int c = 0; c < 2; ++c) {
                int ci = c * 256 + tid;
                int row = ci >> 3, sl = ci & 7;
                kr[c] = *reinterpret_cast<const int4*>(K + (size_t)(b * T + t0 + row) * D + hh * 64 + sl * 8);
                vr[c] = *reinterpret_cast<const int4*>(Vt + (size_t)(bh * 64 + row) * T + t0 + sl * 8);
            }
        }
        // S = Q K^T * sc
        f32x4 s[4];
        #pragma unroll
        for (int ni = 0; ni < 4; ++ni)
            #pragma unroll
            for (int e = 0; e < 4; ++e) s[ni][e] = 0.0f;
        #pragma unroll
        for (int ks = 0; ks < 2; ++ks)
            #pragma unroll
            for (int ni = 0; ni < 4; ++ni) {
                int rk = ni * 16 + (lane & 15);
                int sp = (ks * 4 + (lane >> 4)) ^ (rk & 7);
                bf16x8 kf = *reinterpret_cast<const bf16x8*>((const char*)Ks + rk * 128 + sp * 16);
                s[ni] = __builtin_amdgcn_mfma_f32_16x16x32_bf16(qf[ks], kf, s[ni], 0, 0, 0);
            }
        #pragma unroll
        for (int ni = 0; ni < 4; ++ni)
            #pragma unroll
            for (int jj = 0; jj < 4; ++jj) s[ni][jj] *= sc;
        // online softmax (row lives in 16 lanes sharing lane>>4; reg jj = row)
        float mt[4];
        #pragma unroll
        for (int jj = 0; jj < 4; ++jj)
            mt[jj] = fmaxf(fmaxf(s[0][jj], s[1][jj]), fmaxf(s[2][jj], s[3][jj]));
        #pragma unroll
        for (int off = 1; off < 16; off <<= 1)
            #pragma unroll
            for (int jj = 0; jj < 4; ++jj)
                mt[jj] = fmaxf(mt[jj], __shfl_xor(mt[jj], off, 64));
        float corr[4], psum[4];
        #pragma unroll
        for (int jj = 0; jj < 4; ++jj) {
            float mn = fmaxf(m_run[jj], mt[jj]);
            corr[jj] = __expf(m_run[jj] - mn);
            m_run[jj] = mn;
            psum[jj] = 0.0f;
        }
        #pragma unroll
        for (int ni = 0; ni < 4; ++ni)
            #pragma unroll
            for (int jj = 0; jj < 4; ++jj) {
                float p = __expf(s[ni][jj] - m_run[jj]);
                s[ni][jj] = p;
                psum[jj] += p;
            }
        #pragma unroll
        for (int off = 1; off < 16; off <<= 1)
            #pragma unroll
            for (int jj = 0; jj < 4; ++jj)
                psum[jj] += __shfl_xor(psum[jj], off, 64);
        #pragma unroll
        for (int jj = 0; jj < 4; ++jj)
            l_run[jj] = l_run[jj] * corr[jj] + psum[jj];
        #pragma unroll
        for (int j = 0; j < 4; ++j)
            #pragma unroll
            for (int jj = 0; jj < 4; ++jj)
                o[j][jj] *= corr[jj];
        // P -> LDS (bf16) for transpose into A-fragment layout
        #pragma unroll
        for (int ni = 0; ni < 4; ++ni)
            #pragma unroll
            for (int jj = 0; jj < 4; ++jj)
                Ps[wave * 16 + ((lane >> 4) << 2) + jj][ni * 16 + (lane & 15)] = f2bf(s[ni][jj]);
        // O += P V
        #pragma unroll
        for (int ks = 0; ks < 2; ++ks) {
            bf16x8 pa = *reinterpret_cast<const bf16x8*>(&Ps[wave * 16 + (lane & 15)][ks * 32 + ((lane >> 4) << 3)]);
            #pragma unroll
            for (int j = 0; j < 4; ++j) {
                int rv = j * 16 + (lane & 15);
                int sp = (ks * 4 + (lane >> 4)) ^ (rv & 7);
                bf16x8 vf = *reinterpret_cast<const bf16x8*>((const char*)Vs + rv * 128 + sp * 16);
                o[j] = __builtin_amdgcn_mfma_f32_16x16x32_bf16(pa, vf, o[j], 0, 0, 0);
            }
        }
    }
    #pragma unroll
    for (int jj = 0; jj < 4; ++jj) l_run[jj] = 1.0f / l_run[jj];
    #pragma unroll
    for (int j = 0; j < 4; ++j)
        #pragma unroll
        for (int jj = 0; jj < 4; ++jj) {
            size_t off = (size_t)(b * T + q0 + wave * 16 + ((lane >> 4) << 2) + jj) * D + hh * 64 + j * 16 + (lane & 15);
            AO[off] = f2bf(o[j][jj] * l_run[jj]);
        }
}

// ---------------- output projection + bias + residual ----------------
__global__ __launch_bounds__(256, 2)
void k_ogemm(const u16* __restrict__ A, const u16* __restrict__ Wt,
             const float* __restrict__ bo, const float* __restrict__ xpe,
             float* __restrict__ y)
{
    int m0 = blockIdx.x * 128, n0 = blockIdx.y * 128;
    f32x4 acc[4][4];
    gemm128(A, Wt, m0, n0, acc);
    int lane = threadIdx.x & 63, wave = threadIdx.x >> 6;
    int wr = wave >> 1, wc = wave & 1;
    int rowbase = m0 + wr * 64 + ((lane >> 4) << 2);
    int colbase = n0 + wc * 64 + (lane & 15);
    #pragma unroll
    for (int j = 0; j < 4; ++j) {
        int c = colbase + j * 16;
        float bc = bo[c];
        #pragma unroll
        for (int i = 0; i < 4; ++i) {
            #pragma unroll
            for (int jj = 0; jj < 4; ++jj) {
                int r = rowbase + i * 16 + jj;
                y[(size_t)r * D + c] = acc[i][j][jj] + bc + xpe[(size_t)r * D + c];
            }
        }
    }
}

// ---------------- LayerNorm ----------------
__global__ __launch_bounds__(256) void k_ln(const float* __restrict__ y, const float* __restrict__ g,
                                            const float* __restrict__ bb, float* __restrict__ out)
{
    int row = blockIdx.x;
    int tid = threadIdx.x;
    const float* yr = y + (size_t)row * D;
    float4 v = *reinterpret_cast<const float4*>(yr + tid * 4);
    float s = v.x + v.y + v.z + v.w;
    float s2 = v.x * v.x + v.y * v.y + v.z * v.z + v.w * v.w;
    #pragma unroll
    for (int off = 1; off < 64; off <<= 1) {
        s += __shfl_xor(s, off, 64);
        s2 += __shfl_xor(s2, off, 64);
    }
    __shared__ float red[8];
    int wave = tid >> 6, lane = tid & 63;
    if (lane == 0) { red[wave] = s; red[4 + wave] = s2; }
    __syncthreads();
    s = red[0] + red[1] + red[2] + red[3];
    s2 = red[4] + red[5] + red[6] + red[7];
    float mu = s * (1.0f / 1024.0f);
    float var = s2 * (1.0f / 1024.0f) - mu * mu;
    float rstd = rsqrtf(var + 1e-5f);
    float4 gv = *reinterpret_cast<const float4*>(g + tid * 4);
    float4 bv = *reinterpret_cast<const float4*>(bb + tid * 4);
    float4 o;
    o.x = (v.x - mu) * rstd * gv.x + bv.x;
    o.y = (v.y - mu) * rstd * gv.y + bv.y;
    o.z = (v.z - mu) * rstd * gv.z + bv.z;
    o.w = (v.w - mu) * rstd * gv.w + bv.w;
    *reinterpret_cast<float4*>(out + (size_t)row * D + tid * 4) = o;
}

extern "C" void kernel_launch(void* const* d_in, const int* in_sizes, int n_in,
                              void* d_out, int out_size, void* d_ws, size_t ws_size,
                              hipStream_t stream)
{
    const float* x    = (const float*)d_in[0];
    const float* qtl  = (const float*)d_in[1];
    const float* qimp = (const float*)d_in[2];
    const float* Wq = (const float*)d_in[3];
    const float* bq = (const float*)d_in[4];
    const float* Wk = (const float*)d_in[5];
    const float* bk = (const float*)d_in[6];
    const float* Wv = (const float*)d_in[7];
    const float* bv = (const float*)d_in[8];
    const float* Wo = (const float*)d_in[9];
    const float* bo = (const float*)d_in[10];
    const float* qpq_w1 = (const float*)d_in[11];
    const float* qpq_b1 = (const float*)d_in[12];
    const float* qpq_w2 = (const float*)d_in[13];
    const float* qpq_b2 = (const float*)d_in[14];
    const float* qpk_w1 = (const float*)d_in[15];
    const float* qpk_b1 = (const float*)d_in[16];
    const float* qpk_w2 = (const float*)d_in[17];
    const float* qpk_b2 = (const float*)d_in[18];
    const float* qpv_w1 = (const float*)d_in[19];
    const float* qpv_b1 = (const float*)d_in[20];
    const float* qpv_w2 = (const float*)d_in[21];
    const float* qpv_b2 = (const float*)d_in[22];
    const float* ln_g = (const float*)d_in[23];
    const float* ln_b = (const float*)d_in[24];
    (void)in_sizes; (void)n_in; (void)out_size; (void)ws_size;

    char* w = (char*)d_ws;
    float* xpe   = (float*)(w);                         // 16 MB fp32 residual
    u16* xpeb    = (u16*)(w + (16u << 20));             // 8 MB bf16
    u16* Wt      = (u16*)(w + (24u << 20));             // 8 MB: Wq,Wk,Wv,Wo transposed bf16
    u16* Qb      = (u16*)(w + (32u << 20));             // 8 MB bf16 [NR][D]
    u16* Kb      = (u16*)(w + (40u << 20));             // 8 MB bf16 [NR][D]
    u16* Vtb     = (u16*)(w + (48u << 20));             // 8 MB bf16 [B*NH*64][T]
    u16* AOb     = (u16*)(w + (56u << 20));             // 8 MB bf16 [NR][D]
    float* yb    = (float*)(w + (32u << 20));           // 16 MB fp32, aliases Qb/Kb (dead then)
    float* emb   = (float*)(w + (64u << 20));           // [3][B][D]
    float* scl   = (float*)(w + (64u << 20) + 32768);   // [B]
    float* part  = (float*)(w + (64u << 20) + 65536);   // [6][4][D]

    k_mlp1<<<dim3(4, 4, 6), 256, 0, stream>>>(qtl,
        qpq_w1, qpq_b1, qpq_w2,
        qpk_w1, qpk_b1, qpk_w2,
        qpv_w1, qpv_b1, qpv_w2,
        qimp, part, scl);
    k_mlp2<<<dim3(4, 6), 256, 0, stream>>>(part, qpq_b2, qpk_b2, qpv_b2, emb);
    k_pe<<<4096, 256, 0, stream>>>(x, xpe, xpeb);
    k_wconv<<<dim3(16, 16, 4), 256, 0, stream>>>(Wq, Wk, Wv, Wo, Wt);
    k_qkv<<<dim3(32, 8, 3), 256, 0, stream>>>(xpeb, Wt, bq, bk, bv, emb, Qb, Kb, Vtb);
    k_attn<<<dim3(32, 32), 256, 0, stream>>>(Qb, Kb, Vtb, scl, AOb);
    k_ogemm<<<dim3(32, 8), 256, 0, stream>>>(AOb, Wt + (size_t)3 * D * D, bo, xpe, yb);
    k_ln<<<4096, 256, 0, stream>>>(yb, ln_g, ln_b, (float*)d_out);
}

// Round 2
// 211.026 us; speedup vs baseline: 1.8778x; 1.8778x over previous
//
#include <hip/hip_runtime.h>

#define D 1024
#define T 2048
#define BATCH 2
#define NR 4096
#define NH 16
#define HID 512

typedef unsigned short u16;
typedef unsigned int u32;
typedef float f32x4 __attribute__((ext_vector_type(4)));
typedef __bf16 bf16x8 __attribute__((ext_vector_type(8)));

__device__ __forceinline__ u16 f2bf(float f) {
    union { float f; u32 u; } v; v.f = f;
    u32 r = v.u + 0x7fffu + ((v.u >> 16) & 1u);
    return (u16)(r >> 16);
}

// async global->LDS, 16B per lane. LDS dest is wave-uniform base + lane*16 (linear);
// the read-side XOR swizzle is realized by pre-swizzling the GLOBAL source column.
__device__ __forceinline__ void gload16(const u16* g, u16* l) {
    __builtin_amdgcn_global_load_lds(
        (const __attribute__((address_space(1))) unsigned int*)g,
        (__attribute__((address_space(3))) unsigned int*)l,
        16, 0, 0);
}

// ---------------- quantile MLP stage 1: partial sums + importance scale ----------------
__global__ __launch_bounds__(256) void k_mlp1(const float* __restrict__ qtl,
        const float* __restrict__ w1q, const float* __restrict__ b1q, const float* __restrict__ w2q,
        const float* __restrict__ w1k, const float* __restrict__ b1k, const float* __restrict__ w2k,
        const float* __restrict__ w1v, const float* __restrict__ b1v, const float* __restrict__ w2v,
        const float* __restrict__ qimp, float* __restrict__ part, float* __restrict__ scl)
{
    int dc = blockIdx.x;       // 0..3  (256 d each)
    int jc = blockIdx.y;       // 0..3  (128 j each)
    int wb = blockIdx.z;       // 0..5 : which*2 + b
    int which = wb >> 1, b = wb & 1;
    const float *w1, *b1, *w2;
    if (which == 0)      { w1 = w1q; b1 = b1q; w2 = w2q; }
    else if (which == 1) { w1 = w1k; b1 = b1k; w2 = w2k; }
    else                 { w1 = w1v; b1 = b1v; w2 = w2v; }
    int tid = threadIdx.x;
    __shared__ float h[128];
    if (tid < 128) {
        int j = jc * 128 + tid;
        h[tid] = fmaxf(qtl[b] * w1[j] + b1[j], 0.0f);
    }
    __syncthreads();
    int d = dc * 256 + tid;
    float acc = 0.0f;
    for (int j = 0; j < 128; ++j) acc += h[j] * w2[(size_t)(jc * 128 + j) * D + d];
    part[((size_t)wb * 4 + jc) * D + d] = acc;
    if (dc == 0 && jc == 0 && wb == 0 && tid < BATCH) {
        float mx = qimp[0];
        for (int i = 1; i < 100; ++i) mx = fmaxf(mx, qimp[i]);
        float q = qtl[tid];
        int idx = (int)(q * 100.0f);
        idx = idx < 0 ? 0 : (idx > 99 ? 99 : idx);
        float imp = qimp[idx];
        if (mx > 0.0f) imp /= mx;
        scl[tid] = 1.0f + imp;
    }
}

// ---------------- quantile MLP stage 2: reduce partials + bias ----------------
__global__ __launch_bounds__(256) void k_mlp2(const float* __restrict__ part,
        const float* __restrict__ b2q, const float* __restrict__ b2k, const float* __restrict__ b2v,
        float* __restrict__ embeds)
{
    int dc = blockIdx.x;   // 0..3
    int wb = blockIdx.y;   // 0..5
    int which = wb >> 1;
    const float* b2 = which == 0 ? b2q : which == 1 ? b2k : b2v;
    int d = dc * 256 + threadIdx.x;
    float acc = b2[d];
    #pragma unroll
    for (int jc = 0; jc < 4; ++jc) acc += part[((size_t)wb * 4 + jc) * D + d];
    embeds[(size_t)wb * D + d] = acc;   // [which][b][d]
}

// ---------------- x + sinusoidal PE; fp32 residual copy + bf16 copy ----------------
__global__ __launch_bounds__(256) void k_pe(const float* __restrict__ x,
                                            float* __restrict__ xpe, u16* __restrict__ xpeb)
{
    int idx = (blockIdx.x * 256 + threadIdx.x) * 4;
    int d = idx & (D - 1);
    int t = (idx >> 10) & (T - 1);
    const float KL = -0.0089944731946f;  // -ln(10000)/1024
    float ft = (float)t;
    float dv0 = __expf((float)d * KL);
    float dv1 = __expf((float)(d + 2) * KL);
    float a0 = ft * dv0, a1 = ft * dv1;
    float4 xv = *reinterpret_cast<const float4*>(x + idx);
    float4 r;
    r.x = xv.x + __sinf(a0);
    r.y = xv.y + __cosf(a0);
    r.z = xv.z + __sinf(a1);
    r.w = xv.w + __cosf(a1);
    *reinterpret_cast<float4*>(xpe + idx) = r;
    ushort4 o;
    o.x = f2bf(r.x); o.y = f2bf(r.y); o.z = f2bf(r.z); o.w = f2bf(r.w);
    *reinterpret_cast<ushort4*>(xpeb + idx) = o;
}

// ---------------- weight transpose + bf16 convert: Wt[n][k] = bf16(W[k][n]) ----------------
__global__ __launch_bounds__(256) void k_wconv(const float* __restrict__ Wq, const float* __restrict__ Wk,
                                               const float* __restrict__ Wv, const float* __restrict__ Wo,
                                               u16* __restrict__ Wt)
{
    __shared__ float tile[64][65];
    int z = blockIdx.z;
    const float* W = z == 0 ? Wq : z == 1 ? Wk : z == 2 ? Wv : Wo;
    u16* out = Wt + (size_t)z * D * D;
    int n0 = blockIdx.x * 64, k0 = blockIdx.y * 64;
    int r = threadIdx.x >> 4;
    int c4 = (threadIdx.x & 15) * 4;
    #pragma unroll
    for (int rr = 0; rr < 64; rr += 16) {
        float4 v = *reinterpret_cast<const float4*>(W + (size_t)(k0 + r + rr) * D + n0 + c4);
        tile[r + rr][c4 + 0] = v.x; tile[r + rr][c4 + 1] = v.y;
        tile[r + rr][c4 + 2] = v.z; tile[r + rr][c4 + 3] = v.w;
    }
    __syncthreads();
    #pragma unroll
    for (int rr = 0; rr < 64; rr += 16) {
        ushort4 o;
        o.x = f2bf(tile[c4 + 0][r + rr]);
        o.y = f2bf(tile[c4 + 1][r + rr]);
        o.z = f2bf(tile[c4 + 2][r + rr]);
        o.w = f2bf(tile[c4 + 3][r + rr]);
        *reinterpret_cast<ushort4*>(out + (size_t)(n0 + r + rr) * D + k0 + c4) = o;
    }
}

// ---------------- shared 128x128 bf16 MFMA GEMM core (K=1024, BK=64, m97 structure) ----------------
// A[m][k] row-major bf16, B = Wt[n][k] row-major bf16 (i.e. B^T layout).
__device__ __forceinline__ void gemm128(const u16* __restrict__ Ag, const u16* __restrict__ Bg,
                                        int m0, int n0, f32x4 acc[4][4])
{
    __shared__ u16 As[128 * 64];
    __shared__ u16 Bs[128 * 64];
    const int tid = threadIdx.x;
    const int lane = tid & 63, wave = tid >> 6;
    const int wr = wave >> 1, wc = wave & 1;
    #pragma unroll
    for (int i = 0; i < 4; ++i)
        #pragma unroll
        for (int j = 0; j < 4; ++j)
            #pragma unroll
            for (int e = 0; e < 4; ++e) acc[i][j][e] = 0.0f;

    for (int kt = 0; kt < 16; ++kt) {
        __syncthreads();   // prev tile fully consumed by all waves
        #pragma unroll
        for (int c = 0; c < 4; ++c) {
            int ci = c * 256 + tid;
            int row = ci >> 3;
            int sl = (ci & 7) ^ (row & 7);   // pre-swizzled global column slot
            gload16(Ag + (size_t)(m0 + row) * D + kt * 64 + sl * 8, As + (size_t)ci * 8);
            gload16(Bg + (size_t)(n0 + row) * D + kt * 64 + sl * 8, Bs + (size_t)ci * 8);
        }
        __syncthreads();   // drains vmcnt(0): staged data visible to all
        #pragma unroll
        for (int ks = 0; ks < 2; ++ks) {
            bf16x8 af[4], bfr[4];
            #pragma unroll
            for (int i = 0; i < 4; ++i) {
                int ra = wr * 64 + i * 16 + (lane & 15);
                int sa = ((ks * 4 + (lane >> 4)) ^ (ra & 7));
                af[i] = *reinterpret_cast<const bf16x8*>((const char*)As + ra * 128 + sa * 16);
                int rb = wc * 64 + i * 16 + (lane & 15);
                int sb = ((ks * 4 + (lane >> 4)) ^ (rb & 7));
                bfr[i] = *reinterpret_cast<const bf16x8*>((const char*)Bs + rb * 128 + sb * 16);
            }
            #pragma unroll
            for (int i = 0; i < 4; ++i)
                #pragma unroll
                for (int j = 0; j < 4; ++j)
                    acc[i][j] = __builtin_amdgcn_mfma_f32_16x16x32_bf16(af[i], bfr[j], acc[i][j], 0, 0, 0);
        }
    }
}

// ---------------- Q/K/V projections ----------------
__global__ __launch_bounds__(256, 2)
void k_qkv(const u16* __restrict__ A, const u16* __restrict__ Wt,
           const float* __restrict__ bq, const float* __restrict__ bk, const float* __restrict__ bv,
           const float* __restrict__ embeds,
           u16* __restrict__ Qo, u16* __restrict__ Ko, u16* __restrict__ Vt)
{
    int which = blockIdx.z;
    const u16* Bg = Wt + (size_t)which * D * D;
    const float* bias = which == 0 ? bq : which == 1 ? bk : bv;
    const float* emb = embeds + which * (BATCH * D);
    int m0 = blockIdx.x * 128, n0 = blockIdx.y * 128;
    f32x4 acc[4][4];
    gemm128(A, Bg, m0, n0, acc);
    int lane = threadIdx.x & 63, wave = threadIdx.x >> 6;
    int wr = wave >> 1, wc = wave & 1;
    int rowbase = m0 + wr * 64 + ((lane >> 4) << 2);
    int colbase = n0 + wc * 64 + (lane & 15);
    if (which < 2) {
        u16* Out = which == 0 ? Qo : Ko;
        #pragma unroll
        for (int j = 0; j < 4; ++j) {
            int c = colbase + j * 16;
            float add0 = bias[c] + emb[c];
            float add1 = bias[c] + emb[D + c];
            #pragma unroll
            for (int i = 0; i < 4; ++i) {
                int rb = rowbase + i * 16;
                #pragma unroll
                for (int jj = 0; jj < 4; ++jj) {
                    int r = rb + jj;
                    Out[(size_t)r * D + c] = f2bf(acc[i][j][jj] + ((r >> 11) ? add1 : add0));
                }
            }
        }
    } else {
        // V stored transposed per-head: Vt[((b*NH + h)*64 + cc)][t]
        #pragma unroll
        for (int j = 0; j < 4; ++j) {
            int c = colbase + j * 16;
            int hh = c >> 6, cc = c & 63;
            float add0 = bias[c] + emb[c];
            float add1 = bias[c] + emb[D + c];
            #pragma unroll
            for (int i = 0; i < 4; ++i) {
                int rb = rowbase + i * 16;
                int bb = rb >> 11;
                int t = rb & (T - 1);
                float add = bb ? add1 : add0;
                ushort4 o;
                o.x = f2bf(acc[i][j][0] + add);
                o.y = f2bf(acc[i][j][1] + add);
                o.z = f2bf(acc[i][j][2] + add);
                o.w = f2bf(acc[i][j][3] + add);
                *reinterpret_cast<ushort4*>(Vt + ((size_t)((bb * NH + hh) * 64 + cc)) * T + t) = o;
            }
        }
    }
}

// ---------------- flash attention: 64 q-rows/block, KV tiles of 64 ----------------
// grid: (bh, qtile) so all q-tiles of one (b,h) share an XCD (id%8 const per bh).
__global__ __launch_bounds__(256, 2)
void k_attn(const u16* __restrict__ Q, const u16* __restrict__ K, const u16* __restrict__ Vt,
            const float* __restrict__ scalep, u16* __restrict__ AO)
{
    __shared__ u16 Ks[64 * 64];
    __shared__ u16 Vs[64 * 64];
    __shared__ u16 Ps[64][72];
    int bh = blockIdx.x;
    int b = bh >> 4, hh = bh & 15;
    int q0 = blockIdx.y * 64;
    int tid = threadIdx.x;
    int lane = tid & 63, wave = tid >> 6;
    float sc = scalep[b] * 0.125f;   // scale / sqrt(64)

    bf16x8 qf[2];
    {
        size_t off = (size_t)(b * T + q0 + wave * 16 + (lane & 15)) * D + hh * 64 + ((lane >> 4) << 3);
        qf[0] = *reinterpret_cast<const bf16x8*>(Q + off);
        qf[1] = *reinterpret_cast<const bf16x8*>(Q + off + 32);
    }

    f32x4 o[4];
    float m_run[4], l_run[4];
    #pragma unroll
    for (int j = 0; j < 4; ++j)
        #pragma unroll
        for (int e = 0; e < 4; ++e) o[j][e] = 0.0f;
    #pragma unroll
    for (int jj = 0; jj < 4; ++jj) { m_run[jj] = -1e30f; l_run[jj] = 0.0f; }

    for (int kt = 0; kt < 32; ++kt) {
        __syncthreads();   // prev K/V tile fully consumed
        #pragma unroll
        for (int c = 0; c < 2; ++c) {
            int ci = c * 256 + tid;
            int row = ci >> 3;
            int sl = (ci & 7) ^ (row & 7);   // pre-swizzled global column slot
            gload16(K + (size_t)(b * T + kt * 64 + row) * D + hh * 64 + sl * 8, Ks + (size_t)ci * 8);
            gload16(Vt + (size_t)(bh * 64 + row) * T + kt * 64 + sl * 8, Vs + (size_t)ci * 8);
        }
        __syncthreads();   // vmcnt(0) drain: tiles visible
        // S = Q K^T * sc
        f32x4 s[4];
        #pragma unroll
        for (int ni = 0; ni < 4; ++ni)
            #pragma unroll
            for (int e = 0; e < 4; ++e) s[ni][e] = 0.0f;
        #pragma unroll
        for (int ks = 0; ks < 2; ++ks)
            #pragma unroll
            for (int ni = 0; ni < 4; ++ni) {
                int rk = ni * 16 + (lane & 15);
                int sp = (ks * 4 + (lane >> 4)) ^ (rk & 7);
                bf16x8 kf = *reinterpret_cast<const bf16x8*>((const char*)Ks + rk * 128 + sp * 16);
                s[ni] = __builtin_amdgcn_mfma_f32_16x16x32_bf16(qf[ks], kf, s[ni], 0, 0, 0);
            }
        #pragma unroll
        for (int ni = 0; ni < 4; ++ni)
            #pragma unroll
            for (int jj = 0; jj < 4; ++jj) s[ni][jj] *= sc;
        // online softmax (row lives in 16 lanes sharing lane>>4; reg jj = row)
        float mt[4];
        #pragma unroll
        for (int jj = 0; jj < 4; ++jj)
            mt[jj] = fmaxf(fmaxf(s[0][jj], s[1][jj]), fmaxf(s[2][jj], s[3][jj]));
        #pragma unroll
        for (int off = 1; off < 16; off <<= 1)
            #pragma unroll
            for (int jj = 0; jj < 4; ++jj)
                mt[jj] = fmaxf(mt[jj], __shfl_xor(mt[jj], off, 64));
        float corr[4], psum[4];
        #pragma unroll
        for (int jj = 0; jj < 4; ++jj) {
            float mn = fmaxf(m_run[jj], mt[jj]);
            corr[jj] = __expf(m_run[jj] - mn);
            m_run[jj] = mn;
            psum[jj] = 0.0f;
        }
        #pragma unroll
        for (int ni = 0; ni < 4; ++ni)
            #pragma unroll
            for (int jj = 0; jj < 4; ++jj) {
                float p = __expf(s[ni][jj] - m_run[jj]);
                s[ni][jj] = p;
                psum[jj] += p;
            }
        #pragma unroll
        for (int off = 1; off < 16; off <<= 1)
            #pragma unroll
            for (int jj = 0; jj < 4; ++jj)
                psum[jj] += __shfl_xor(psum[jj], off, 64);
        #pragma unroll
        for (int jj = 0; jj < 4; ++jj)
            l_run[jj] = l_run[jj] * corr[jj] + psum[jj];
        #pragma unroll
        for (int j = 0; j < 4; ++j)
            #pragma unroll
            for (int jj = 0; jj < 4; ++jj)
                o[j][jj] *= corr[jj];
        // P -> LDS (bf16) for transpose into A-fragment layout (wave-local stripe)
        #pragma unroll
        for (int ni = 0; ni < 4; ++ni)
            #pragma unroll
            for (int jj = 0; jj < 4; ++jj)
                Ps[wave * 16 + ((lane >> 4) << 2) + jj][ni * 16 + (lane & 15)] = f2bf(s[ni][jj]);
        // O += P V
        #pragma unroll
        for (int ks = 0; ks < 2; ++ks) {
            bf16x8 pa = *reinterpret_cast<const bf16x8*>(&Ps[wave * 16 + (lane & 15)][ks * 32 + ((lane >> 4) << 3)]);
            #pragma unroll
            for (int j = 0; j < 4; ++j) {
                int rv = j * 16 + (lane & 15);
                int sp = (ks * 4 + (lane >> 4)) ^ (rv & 7);
                bf16x8 vf = *reinterpret_cast<const bf16x8*>((const char*)Vs + rv * 128 + sp * 16);
                o[j] = __builtin_amdgcn_mfma_f32_16x16x32_bf16(pa, vf, o[j], 0, 0, 0);
            }
        }
    }
    #pragma unroll
    for (int jj = 0; jj < 4; ++jj) l_run[jj] = 1.0f / l_run[jj];
    #pragma unroll
    for (int j = 0; j < 4; ++j)
        #pragma unroll
        for (int jj = 0; jj < 4; ++jj) {
            size_t off = (size_t)(b * T + q0 + wave * 16 + ((lane >> 4) << 2) + jj) * D + hh * 64 + j * 16 + (lane & 15);
            AO[off] = f2bf(o[j][jj] * l_run[jj]);
        }
}

// ---------------- output projection + bias + residual ----------------
__global__ __launch_bounds__(256, 2)
void k_ogemm(const u16* __restrict__ A, const u16* __restrict__ Wt,
             const float* __restrict__ bo, const float* __restrict__ xpe,
             float* __restrict__ y)
{
    int m0 = blockIdx.x * 128, n0 = blockIdx.y * 128;
    f32x4 acc[4][4];
    gemm128(A, Wt, m0, n0, acc);
    int lane = threadIdx.x & 63, wave = threadIdx.x >> 6;
    int wr = wave >> 1, wc = wave & 1;
    int rowbase = m0 + wr * 64 + ((lane >> 4) << 2);
    int colbase = n0 + wc * 64 + (lane & 15);
    #pragma unroll
    for (int j = 0; j < 4; ++j) {
        int c = colbase + j * 16;
        float bc = bo[c];
        #pragma unroll
        for (int i = 0; i < 4; ++i) {
            #pragma unroll
            for (int jj = 0; jj < 4; ++jj) {
                int r = rowbase + i * 16 + jj;
                y[(size_t)r * D + c] = acc[i][j][jj] + bc + xpe[(size_t)r * D + c];
            }
        }
    }
}

// ---------------- LayerNorm ----------------
__global__ __launch_bounds__(256) void k_ln(const float* __restrict__ y, const float* __restrict__ g,
                                            const float* __restrict__ bb, float* __restrict__ out)
{
    int row = blockIdx.x;
    int tid = threadIdx.x;
    const float* yr = y + (size_t)row * D;
    float4 v = *reinterpret_cast<const float4*>(yr + tid * 4);
    float s = v.x + v.y + v.z + v.w;
    float s2 = v.x * v.x + v.y * v.y + v.z * v.z + v.w * v.w;
    #pragma unroll
    for (int off = 1; off < 64; off <<= 1) {
        s += __shfl_xor(s, off, 64);
        s2 += __shfl_xor(s2, off, 64);
    }
    __shared__ float red[8];
    int wave = tid >> 6, lane = tid & 63;
    if (lane == 0) { red[wave] = s; red[4 + wave] = s2; }
    __syncthreads();
    s = red[0] + red[1] + red[2] + red[3];
    s2 = red[4] + red[5] + red[6] + red[7];
    float mu = s * (1.0f / 1024.0f);
    float var = s2 * (1.0f / 1024.0f) - mu * mu;
    float rstd = rsqrtf(var + 1e-5f);
    float4 gv = *reinterpret_cast<const float4*>(g + tid * 4);
    float4 bv = *reinterpret_cast<const float4*>(bb + tid * 4);
    float4 o;
    o.x = (v.x - mu) * rstd * gv.x + bv.x;
    o.y = (v.y - mu) * rstd * gv.y + bv.y;
    o.z = (v.z - mu) * rstd * gv.z + bv.z;
    o.w = (v.w - mu) * rstd * gv.w + bv.w;
    *reinterpret_cast<float4*>(out + (size_t)row * D + tid * 4) = o;
}

extern "C" void kernel_launch(void* const* d_in, const int* in_sizes, int n_in,
                              void* d_out, int out_size, void* d_ws, size_t ws_size,
                              hipStream_t stream)
{
    const float* x    = (const float*)d_in[0];
    const float* qtl  = (const float*)d_in[1];
    const float* qimp = (const float*)d_in[2];
    const float* Wq = (const float*)d_in[3];
    const float* bq = (const float*)d_in[4];
    const float* Wk = (const float*)d_in[5];
    const float* bk = (const float*)d_in[6];
    const float* Wv = (const float*)d_in[7];
    const float* bv = (const float*)d_in[8];
    const float* Wo = (const float*)d_in[9];
    const float* bo = (const float*)d_in[10];
    const float* qpq_w1 = (const float*)d_in[11];
    const float* qpq_b1 = (const float*)d_in[12];
    const float* qpq_w2 = (const float*)d_in[13];
    const float* qpq_b2 = (const float*)d_in[14];
    const float* qpk_w1 = (const float*)d_in[15];
    const float* qpk_b1 = (const float*)d_in[16];
    const float* qpk_w2 = (const float*)d_in[17];
    const float* qpk_b2 = (const float*)d_in[18];
    const float* qpv_w1 = (const float*)d_in[19];
    const float* qpv_b1 = (const float*)d_in[20];
    const float* qpv_w2 = (const float*)d_in[21];
    const float* qpv_b2 = (const float*)d_in[22];
    const float* ln_g = (const float*)d_in[23];
    const float* ln_b = (const float*)d_in[24];
    (void)in_sizes; (void)n_in; (void)out_size; (void)ws_size;

    char* w = (char*)d_ws;
    float* xpe   = (float*)(w);                         // 16 MB fp32 residual
    u16* xpeb    = (u16*)(w + (16u << 20));             // 8 MB bf16
    u16* Wt      = (u16*)(w + (24u << 20));             // 8 MB: Wq,Wk,Wv,Wo transposed bf16
    u16* Qb      = (u16*)(w + (32u << 20));             // 8 MB bf16 [NR][D]
    u16* Kb      = (u16*)(w + (40u << 20));             // 8 MB bf16 [NR][D]
    u16* Vtb     = (u16*)(w + (48u << 20));             // 8 MB bf16 [B*NH*64][T]
    u16* AOb     = (u16*)(w + (56u << 20));             // 8 MB bf16 [NR][D]
    float* yb    = (float*)(w + (32u << 20));           // 16 MB fp32, aliases Qb/Kb (dead then)
    float* emb   = (float*)(w + (64u << 20));           // [3][B][D]
    float* scl   = (float*)(w + (64u << 20) + 32768);   // [B]
    float* part  = (float*)(w + (64u << 20) + 65536);   // [6][4][D]

    k_mlp1<<<dim3(4, 4, 6), 256, 0, stream>>>(qtl,
        qpq_w1, qpq_b1, qpq_w2,
        qpk_w1, qpk_b1, qpk_w2,
        qpv_w1, qpv_b1, qpv_w2,
        qimp, part, scl);
    k_mlp2<<<dim3(4, 6), 256, 0, stream>>>(part, qpq_b2, qpk_b2, qpv_b2, emb);
    k_pe<<<4096, 256, 0, stream>>>(x, xpe, xpeb);
    k_wconv<<<dim3(16, 16, 4), 256, 0, stream>>>(Wq, Wk, Wv, Wo, Wt);
    k_qkv<<<dim3(32, 8, 3), 256, 0, stream>>>(xpeb, Wt, bq, bk, bv, emb, Qb, Kb, Vtb);
    k_attn<<<dim3(32, 32), 256, 0, stream>>>(Qb, Kb, Vtb, scl, AOb);
    k_ogemm<<<dim3(32, 8), 256, 0, stream>>>(AOb, Wt + (size_t)3 * D * D, bo, xpe, yb);
    k_ln<<<4096, 256, 0, stream>>>(yb, ln_g, ln_b, (float*)d_out);
}

// Round 3
// 181.974 us; speedup vs baseline: 2.1776x; 1.1596x over previous
//
#include <hip/hip_runtime.h>

#define D 1024
#define T 2048
#define BATCH 2
#define NR 4096
#define NH 16
#define HID 512

typedef unsigned short u16;
typedef unsigned int u32;
typedef float f32x4 __attribute__((ext_vector_type(4)));
typedef __bf16 bf16x8 __attribute__((ext_vector_type(8)));

// native RNE f32->bf16 (hardware v_cvt; m240: compiler handles scalar casts well)
__device__ __forceinline__ u16 f2bf(float f) {
    union { __bf16 h; u16 u; } c; c.h = (__bf16)f; return c.u;
}

// async global->LDS, 16B per lane. LDS dest is wave-uniform base + lane*16 (linear);
// the read-side XOR swizzle is realized by pre-swizzling the GLOBAL source column.
__device__ __forceinline__ void gload16(const u16* g, u16* l) {
    __builtin_amdgcn_global_load_lds(
        (const __attribute__((address_space(1))) unsigned int*)g,
        (__attribute__((address_space(3))) unsigned int*)l,
        16, 0, 0);
}

// ---------------- quantile MLP stage 1: partial sums + importance scale ----------------
__global__ __launch_bounds__(256) void k_mlp1(const float* __restrict__ qtl,
        const float* __restrict__ w1q, const float* __restrict__ b1q, const float* __restrict__ w2q,
        const float* __restrict__ w1k, const float* __restrict__ b1k, const float* __restrict__ w2k,
        const float* __restrict__ w1v, const float* __restrict__ b1v, const float* __restrict__ w2v,
        const float* __restrict__ qimp, float* __restrict__ part, float* __restrict__ scl)
{
    int dc = blockIdx.x;       // 0..3  (256 d each)
    int jc = blockIdx.y;       // 0..3  (128 j each)
    int wb = blockIdx.z;       // 0..5 : which*2 + b
    int which = wb >> 1, b = wb & 1;
    const float *w1, *b1, *w2;
    if (which == 0)      { w1 = w1q; b1 = b1q; w2 = w2q; }
    else if (which == 1) { w1 = w1k; b1 = b1k; w2 = w2k; }
    else                 { w1 = w1v; b1 = b1v; w2 = w2v; }
    int tid = threadIdx.x;
    __shared__ float h[128];
    if (tid < 128) {
        int j = jc * 128 + tid;
        h[tid] = fmaxf(qtl[b] * w1[j] + b1[j], 0.0f);
    }
    __syncthreads();
    int d = dc * 256 + tid;
    float acc = 0.0f;
    for (int j = 0; j < 128; ++j) acc += h[j] * w2[(size_t)(jc * 128 + j) * D + d];
    part[((size_t)wb * 4 + jc) * D + d] = acc;
    if (dc == 0 && jc == 0 && wb == 0 && tid < BATCH) {
        float mx = qimp[0];
        for (int i = 1; i < 100; ++i) mx = fmaxf(mx, qimp[i]);
        float q = qtl[tid];
        int idx = (int)(q * 100.0f);
        idx = idx < 0 ? 0 : (idx > 99 ? 99 : idx);
        float imp = qimp[idx];
        if (mx > 0.0f) imp /= mx;
        scl[tid] = 1.0f + imp;
    }
}

// ---------------- quantile MLP stage 2: reduce partials + bias ----------------
__global__ __launch_bounds__(256) void k_mlp2(const float* __restrict__ part,
        const float* __restrict__ b2q, const float* __restrict__ b2k, const float* __restrict__ b2v,
        float* __restrict__ embeds)
{
    int dc = blockIdx.x;   // 0..3
    int wb = blockIdx.y;   // 0..5
    int which = wb >> 1;
    const float* b2 = which == 0 ? b2q : which == 1 ? b2k : b2v;
    int d = dc * 256 + threadIdx.x;
    float acc = b2[d];
    #pragma unroll
    for (int jc = 0; jc < 4; ++jc) acc += part[((size_t)wb * 4 + jc) * D + d];
    embeds[(size_t)wb * D + d] = acc;   // [which][b][d]
}

// ---------------- x + sinusoidal PE; fp32 residual copy + bf16 copy ----------------
__global__ __launch_bounds__(256) void k_pe(const float* __restrict__ x,
                                            float* __restrict__ xpe, u16* __restrict__ xpeb)
{
    int idx = (blockIdx.x * 256 + threadIdx.x) * 4;
    int d = idx & (D - 1);
    int t = (idx >> 10) & (T - 1);
    const float KL = -0.0089944731946f;  // -ln(10000)/1024
    float ft = (float)t;
    float dv0 = __expf((float)d * KL);
    float dv1 = __expf((float)(d + 2) * KL);
    float a0 = ft * dv0, a1 = ft * dv1;
    float4 xv = *reinterpret_cast<const float4*>(x + idx);
    float4 r;
    r.x = xv.x + __sinf(a0);
    r.y = xv.y + __cosf(a0);
    r.z = xv.z + __sinf(a1);
    r.w = xv.w + __cosf(a1);
    *reinterpret_cast<float4*>(xpe + idx) = r;
    ushort4 o;
    o.x = f2bf(r.x); o.y = f2bf(r.y); o.z = f2bf(r.z); o.w = f2bf(r.w);
    *reinterpret_cast<ushort4*>(xpeb + idx) = o;
}

// ---------------- weight transpose + bf16 convert: Wt[n][k] = bf16(W[k][n]) ----------------
__global__ __launch_bounds__(256) void k_wconv(const float* __restrict__ Wq, const float* __restrict__ Wk,
                                               const float* __restrict__ Wv, const float* __restrict__ Wo,
                                               u16* __restrict__ Wt)
{
    __shared__ float tile[64][65];
    int z = blockIdx.z;
    const float* W = z == 0 ? Wq : z == 1 ? Wk : z == 2 ? Wv : Wo;
    u16* out = Wt + (size_t)z * D * D;
    int n0 = blockIdx.x * 64, k0 = blockIdx.y * 64;
    int r = threadIdx.x >> 4;
    int c4 = (threadIdx.x & 15) * 4;
    #pragma unroll
    for (int rr = 0; rr < 64; rr += 16) {
        float4 v = *reinterpret_cast<const float4*>(W + (size_t)(k0 + r + rr) * D + n0 + c4);
        tile[r + rr][c4 + 0] = v.x; tile[r + rr][c4 + 1] = v.y;
        tile[r + rr][c4 + 2] = v.z; tile[r + rr][c4 + 3] = v.w;
    }
    __syncthreads();
    #pragma unroll
    for (int rr = 0; rr < 64; rr += 16) {
        ushort4 o;
        o.x = f2bf(tile[c4 + 0][r + rr]);
        o.y = f2bf(tile[c4 + 1][r + rr]);
        o.z = f2bf(tile[c4 + 2][r + rr]);
        o.w = f2bf(tile[c4 + 3][r + rr]);
        *reinterpret_cast<ushort4*>(out + (size_t)(n0 + r + rr) * D + k0 + c4) = o;
    }
}

// ---------------- shared 128x128 bf16 MFMA GEMM core (K=1024, BK=64, m97 structure) ----------------
// A[m][k] row-major bf16, B = Wt[n][k] row-major bf16 (i.e. B^T layout).
__device__ __forceinline__ void gemm128(const u16* __restrict__ Ag, const u16* __restrict__ Bg,
                                        int m0, int n0, f32x4 acc[4][4])
{
    __shared__ u16 As[128 * 64];
    __shared__ u16 Bs[128 * 64];
    const int tid = threadIdx.x;
    const int lane = tid & 63, wave = tid >> 6;
    const int wr = wave >> 1, wc = wave & 1;
    #pragma unroll
    for (int i = 0; i < 4; ++i)
        #pragma unroll
        for (int j = 0; j < 4; ++j)
            #pragma unroll
            for (int e = 0; e < 4; ++e) acc[i][j][e] = 0.0f;

    for (int kt = 0; kt < 16; ++kt) {
        __syncthreads();   // prev tile fully consumed by all waves
        #pragma unroll
        for (int c = 0; c < 4; ++c) {
            int ci = c * 256 + tid;
            int row = ci >> 3;
            int sl = (ci & 7) ^ (row & 7);   // pre-swizzled global column slot
            gload16(Ag + (size_t)(m0 + row) * D + kt * 64 + sl * 8, As + (size_t)ci * 8);
            gload16(Bg + (size_t)(n0 + row) * D + kt * 64 + sl * 8, Bs + (size_t)ci * 8);
        }
        __syncthreads();   // drains vmcnt(0): staged data visible to all
        #pragma unroll
        for (int ks = 0; ks < 2; ++ks) {
            bf16x8 af[4], bfr[4];
            #pragma unroll
            for (int i = 0; i < 4; ++i) {
                int ra = wr * 64 + i * 16 + (lane & 15);
                int sa = ((ks * 4 + (lane >> 4)) ^ (ra & 7));
                af[i] = *reinterpret_cast<const bf16x8*>((const char*)As + ra * 128 + sa * 16);
                int rb = wc * 64 + i * 16 + (lane & 15);
                int sb = ((ks * 4 + (lane >> 4)) ^ (rb & 7));
                bfr[i] = *reinterpret_cast<const bf16x8*>((const char*)Bs + rb * 128 + sb * 16);
            }
            #pragma unroll
            for (int i = 0; i < 4; ++i)
                #pragma unroll
                for (int j = 0; j < 4; ++j)
                    acc[i][j] = __builtin_amdgcn_mfma_f32_16x16x32_bf16(af[i], bfr[j], acc[i][j], 0, 0, 0);
        }
    }
}

// ---------------- Q/K/V projections (Q pre-scaled by scl[b]/sqrt(dk)) ----------------
__global__ __launch_bounds__(256, 2)
void k_qkv(const u16* __restrict__ A, const u16* __restrict__ Wt,
           const float* __restrict__ bq, const float* __restrict__ bk, const float* __restrict__ bv,
           const float* __restrict__ embeds, const float* __restrict__ scl,
           u16* __restrict__ Qo, u16* __restrict__ Ko, u16* __restrict__ Vt)
{
    int which = blockIdx.z;
    const u16* Bg = Wt + (size_t)which * D * D;
    const float* bias = which == 0 ? bq : which == 1 ? bk : bv;
    const float* emb = embeds + which * (BATCH * D);
    int m0 = blockIdx.x * 128, n0 = blockIdx.y * 128;
    f32x4 acc[4][4];
    gemm128(A, Bg, m0, n0, acc);
    int lane = threadIdx.x & 63, wave = threadIdx.x >> 6;
    int wr = wave >> 1, wc = wave & 1;
    int rowbase = m0 + wr * 64 + ((lane >> 4) << 2);
    int colbase = n0 + wc * 64 + (lane & 15);
    if (which < 2) {
        u16* Out = which == 0 ? Qo : Ko;
        float sc0 = 1.0f, sc1 = 1.0f;
        if (which == 0) { sc0 = scl[0] * 0.125f; sc1 = scl[1] * 0.125f; }
        #pragma unroll
        for (int j = 0; j < 4; ++j) {
            int c = colbase + j * 16;
            float add0 = bias[c] + emb[c];
            float add1 = bias[c] + emb[D + c];
            #pragma unroll
            for (int i = 0; i < 4; ++i) {
                int rb = rowbase + i * 16;
                #pragma unroll
                for (int jj = 0; jj < 4; ++jj) {
                    int r = rb + jj;
                    float v = (r >> 11) ? (acc[i][j][jj] + add1) * sc1
                                        : (acc[i][j][jj] + add0) * sc0;
                    Out[(size_t)r * D + c] = f2bf(v);
                }
            }
        }
    } else {
        // V stored transposed per-head: Vt[((b*NH + h)*64 + cc)][t]
        #pragma unroll
        for (int j = 0; j < 4; ++j) {
            int c = colbase + j * 16;
            int hh = c >> 6, cc = c & 63;
            float add0 = bias[c] + emb[c];
            float add1 = bias[c] + emb[D + c];
            #pragma unroll
            for (int i = 0; i < 4; ++i) {
                int rb = rowbase + i * 16;
                int bb = rb >> 11;
                int t = rb & (T - 1);
                float add = bb ? add1 : add0;
                ushort4 o;
                o.x = f2bf(acc[i][j][0] + add);
                o.y = f2bf(acc[i][j][1] + add);
                o.z = f2bf(acc[i][j][2] + add);
                o.w = f2bf(acc[i][j][3] + add);
                *reinterpret_cast<ushort4*>(Vt + ((size_t)((bb * NH + hh) * 64 + cc)) * T + t) = o;
            }
        }
    }
}

// ---------------- flash attention: QBLK=128 (8 waves), KVBLK=128 ----------------
// grid: (bh, qtile) so all q-tiles of one (b,h) share an XCD (id%8 const per bh).
// scale already folded into Q. defer-max (T13, THR=8).
__global__ __launch_bounds__(512, 2)
void k_attn(const u16* __restrict__ Q, const u16* __restrict__ K, const u16* __restrict__ Vt,
            u16* __restrict__ AO)
{
    __shared__ u16 Ks[128 * 64];    // [t=128][d=64], 8x16B slots/row, slot^=(row&7)
    __shared__ u16 Vs[64 * 128];    // [d=64][t=128], 16x16B slots/row, slot^=(row&7)
    __shared__ u16 Ps[128][136];    // [q][k], row stride 272B = 17*16B (self-swizzling)
    int bh = blockIdx.x;
    int b = bh >> 4, hh = bh & 15;
    int q0 = blockIdx.y * 128;
    int tid = threadIdx.x;
    int lane = tid & 63, wave = tid >> 6;

    bf16x8 qf[2];
    {
        size_t off = (size_t)(b * T + q0 + wave * 16 + (lane & 15)) * D + hh * 64 + ((lane >> 4) << 3);
        qf[0] = *reinterpret_cast<const bf16x8*>(Q + off);
        qf[1] = *reinterpret_cast<const bf16x8*>(Q + off + 32);
    }

    f32x4 o[4];
    float m_run[4], l_run[4];
    #pragma unroll
    for (int j = 0; j < 4; ++j)
        #pragma unroll
        for (int e = 0; e < 4; ++e) o[j][e] = 0.0f;
    #pragma unroll
    for (int jj = 0; jj < 4; ++jj) { m_run[jj] = -1e30f; l_run[jj] = 0.0f; }

    for (int kt = 0; kt < 16; ++kt) {
        __syncthreads();   // prev K/V tile fully consumed
        #pragma unroll
        for (int c = 0; c < 2; ++c) {
            int ci = c * 512 + tid;
            int row = ci >> 3;                  // 0..127 (t)
            int sl = (ci & 7) ^ (row & 7);
            gload16(K + (size_t)(b * T + kt * 128 + row) * D + hh * 64 + sl * 8, Ks + (size_t)ci * 8);
            int rowv = ci >> 4;                 // 0..63 (d)
            int slv = (ci & 15) ^ (rowv & 7);
            gload16(Vt + (size_t)(bh * 64 + rowv) * T + kt * 128 + slv * 8, Vs + (size_t)ci * 8);
        }
        __syncthreads();   // vmcnt(0) drain: tiles visible
        // S = Q K^T (scale pre-folded into Q)
        f32x4 s[8];
        #pragma unroll
        for (int ni = 0; ni < 8; ++ni)
            #pragma unroll
            for (int e = 0; e < 4; ++e) s[ni][e] = 0.0f;
        #pragma unroll
        for (int ks = 0; ks < 2; ++ks)
            #pragma unroll
            for (int ni = 0; ni < 8; ++ni) {
                int rk = ni * 16 + (lane & 15);
                int sp = (ks * 4 + (lane >> 4)) ^ (rk & 7);
                bf16x8 kf = *reinterpret_cast<const bf16x8*>((const char*)Ks + rk * 128 + sp * 16);
                s[ni] = __builtin_amdgcn_mfma_f32_16x16x32_bf16(qf[ks], kf, s[ni], 0, 0, 0);
            }
        // online softmax; rows = wave stripe, reg jj = row, k over (lane&15, ni)
        float mt[4];
        #pragma unroll
        for (int jj = 0; jj < 4; ++jj) {
            float a = fmaxf(fmaxf(s[0][jj], s[1][jj]), fmaxf(s[2][jj], s[3][jj]));
            float c2 = fmaxf(fmaxf(s[4][jj], s[5][jj]), fmaxf(s[6][jj], s[7][jj]));
            mt[jj] = fmaxf(a, c2);
        }
        #pragma unroll
        for (int off = 1; off < 16; off <<= 1)
            #pragma unroll
            for (int jj = 0; jj < 4; ++jj)
                mt[jj] = fmaxf(mt[jj], __shfl_xor(mt[jj], off, 64));
        bool ok = (mt[0] <= m_run[0] + 8.0f) && (mt[1] <= m_run[1] + 8.0f) &&
                  (mt[2] <= m_run[2] + 8.0f) && (mt[3] <= m_run[3] + 8.0f);
        bool skip = __all((int)ok);
        float corr[4];
        if (!skip) {
            #pragma unroll
            for (int jj = 0; jj < 4; ++jj) {
                float mn = fmaxf(m_run[jj], mt[jj]);
                corr[jj] = __expf(m_run[jj] - mn);
                m_run[jj] = mn;
            }
        }
        float psum[4];
        #pragma unroll
        for (int jj = 0; jj < 4; ++jj) psum[jj] = 0.0f;
        #pragma unroll
        for (int ni = 0; ni < 8; ++ni)
            #pragma unroll
            for (int jj = 0; jj < 4; ++jj) {
                float p = __expf(s[ni][jj] - m_run[jj]);
                s[ni][jj] = p;
                psum[jj] += p;
            }
        #pragma unroll
        for (int off = 1; off < 16; off <<= 1)
            #pragma unroll
            for (int jj = 0; jj < 4; ++jj)
                psum[jj] += __shfl_xor(psum[jj], off, 64);
        if (!skip) {
            #pragma unroll
            for (int jj = 0; jj < 4; ++jj)
                l_run[jj] = l_run[jj] * corr[jj] + psum[jj];
            #pragma unroll
            for (int j = 0; j < 4; ++j)
                #pragma unroll
                for (int jj = 0; jj < 4; ++jj)
                    o[j][jj] *= corr[jj];
        } else {
            #pragma unroll
            for (int jj = 0; jj < 4; ++jj) l_run[jj] += psum[jj];
        }
        // P -> LDS (bf16); wave-local stripe, no barrier needed
        #pragma unroll
        for (int ni = 0; ni < 8; ++ni)
            #pragma unroll
            for (int jj = 0; jj < 4; ++jj)
                Ps[wave * 16 + ((lane >> 4) << 2) + jj][ni * 16 + (lane & 15)] = f2bf(s[ni][jj]);
        // O += P V
        #pragma unroll
        for (int ks2 = 0; ks2 < 4; ++ks2) {
            bf16x8 pa = *reinterpret_cast<const bf16x8*>(
                (const char*)&Ps[wave * 16 + (lane & 15)][0] + ks2 * 64 + ((lane >> 4) << 4));
            #pragma unroll
            for (int j = 0; j < 4; ++j) {
                int rv = j * 16 + (lane & 15);
                int spv = (ks2 * 4 + (lane >> 4)) ^ (rv & 7);
                bf16x8 vf = *reinterpret_cast<const bf16x8*>((const char*)Vs + rv * 256 + spv * 16);
                o[j] = __builtin_amdgcn_mfma_f32_16x16x32_bf16(pa, vf, o[j], 0, 0, 0);
            }
        }
    }
    #pragma unroll
    for (int jj = 0; jj < 4; ++jj) l_run[jj] = 1.0f / l_run[jj];
    #pragma unroll
    for (int j = 0; j < 4; ++j)
        #pragma unroll
        for (int jj = 0; jj < 4; ++jj) {
            size_t off = (size_t)(b * T + q0 + wave * 16 + ((lane >> 4) << 2) + jj) * D + hh * 64 + j * 16 + (lane & 15);
            AO[off] = f2bf(o[j][jj] * l_run[jj]);
        }
}

// ---------------- output projection + bias + residual ----------------
__global__ __launch_bounds__(256, 2)
void k_ogemm(const u16* __restrict__ A, const u16* __restrict__ Wt,
             const float* __restrict__ bo, const float* __restrict__ xpe,
             float* __restrict__ y)
{
    int m0 = blockIdx.x * 128, n0 = blockIdx.y * 128;
    f32x4 acc[4][4];
    gemm128(A, Wt, m0, n0, acc);
    int lane = threadIdx.x & 63, wave = threadIdx.x >> 6;
    int wr = wave >> 1, wc = wave & 1;
    int rowbase = m0 + wr * 64 + ((lane >> 4) << 2);
    int colbase = n0 + wc * 64 + (lane & 15);
    #pragma unroll
    for (int j = 0; j < 4; ++j) {
        int c = colbase + j * 16;
        float bc = bo[c];
        #pragma unroll
        for (int i = 0; i < 4; ++i) {
            #pragma unroll
            for (int jj = 0; jj < 4; ++jj) {
                int r = rowbase + i * 16 + jj;
                y[(size_t)r * D + c] = acc[i][j][jj] + bc + xpe[(size_t)r * D + c];
            }
        }
    }
}

// ---------------- LayerNorm ----------------
__global__ __launch_bounds__(256) void k_ln(const float* __restrict__ y, const float* __restrict__ g,
                                            const float* __restrict__ bb, float* __restrict__ out)
{
    int row = blockIdx.x;
    int tid = threadIdx.x;
    const float* yr = y + (size_t)row * D;
    float4 v = *reinterpret_cast<const float4*>(yr + tid * 4);
    float s = v.x + v.y + v.z + v.w;
    float s2 = v.x * v.x + v.y * v.y + v.z * v.z + v.w * v.w;
    #pragma unroll
    for (int off = 1; off < 64; off <<= 1) {
        s += __shfl_xor(s, off, 64);
        s2 += __shfl_xor(s2, off, 64);
    }
    __shared__ float red[8];
    int wave = tid >> 6, lane = tid & 63;
    if (lane == 0) { red[wave] = s; red[4 + wave] = s2; }
    __syncthreads();
    s = red[0] + red[1] + red[2] + red[3];
    s2 = red[4] + red[5] + red[6] + red[7];
    float mu = s * (1.0f / 1024.0f);
    float var = s2 * (1.0f / 1024.0f) - mu * mu;
    float rstd = rsqrtf(var + 1e-5f);
    float4 gv = *reinterpret_cast<const float4*>(g + tid * 4);
    float4 bv = *reinterpret_cast<const float4*>(bb + tid * 4);
    float4 o;
    o.x = (v.x - mu) * rstd * gv.x + bv.x;
    o.y = (v.y - mu) * rstd * gv.y + bv.y;
    o.z = (v.z - mu) * rstd * gv.z + bv.z;
    o.w = (v.w - mu) * rstd * gv.w + bv.w;
    *reinterpret_cast<float4*>(out + (size_t)row * D + tid * 4) = o;
}

extern "C" void kernel_launch(void* const* d_in, const int* in_sizes, int n_in,
                              void* d_out, int out_size, void* d_ws, size_t ws_size,
                              hipStream_t stream)
{
    const float* x    = (const float*)d_in[0];
    const float* qtl  = (const float*)d_in[1];
    const float* qimp = (const float*)d_in[2];
    const float* Wq = (const float*)d_in[3];
    const float* bq = (const float*)d_in[4];
    const float* Wk = (const float*)d_in[5];
    const float* bk = (const float*)d_in[6];
    const float* Wv = (const float*)d_in[7];
    const float* bv = (const float*)d_in[8];
    const float* Wo = (const float*)d_in[9];
    const float* bo = (const float*)d_in[10];
    const float* qpq_w1 = (const float*)d_in[11];
    const float* qpq_b1 = (const float*)d_in[12];
    const float* qpq_w2 = (const float*)d_in[13];
    const float* qpq_b2 = (const float*)d_in[14];
    const float* qpk_w1 = (const float*)d_in[15];
    const float* qpk_b1 = (const float*)d_in[16];
    const float* qpk_w2 = (const float*)d_in[17];
    const float* qpk_b2 = (const float*)d_in[18];
    const float* qpv_w1 = (const float*)d_in[19];
    const float* qpv_b1 = (const float*)d_in[20];
    const float* qpv_w2 = (const float*)d_in[21];
    const float* qpv_b2 = (const float*)d_in[22];
    const float* ln_g = (const float*)d_in[23];
    const float* ln_b = (const float*)d_in[24];
    (void)in_sizes; (void)n_in; (void)out_size; (void)ws_size;

    char* w = (char*)d_ws;
    float* xpe   = (float*)(w);                         // 16 MB fp32 residual
    u16* xpeb    = (u16*)(w + (16u << 20));             // 8 MB bf16
    u16* Wt      = (u16*)(w + (24u << 20));             // 8 MB: Wq,Wk,Wv,Wo transposed bf16
    u16* Qb      = (u16*)(w + (32u << 20));             // 8 MB bf16 [NR][D]
    u16* Kb      = (u16*)(w + (40u << 20));             // 8 MB bf16 [NR][D]
    u16* Vtb     = (u16*)(w + (48u << 20));             // 8 MB bf16 [B*NH*64][T]
    u16* AOb     = (u16*)(w + (56u << 20));             // 8 MB bf16 [NR][D]
    float* yb    = (float*)(w + (32u << 20));           // 16 MB fp32, aliases Qb/Kb (dead then)
    float* emb   = (float*)(w + (64u << 20));           // [3][B][D]
    float* scl   = (float*)(w + (64u << 20) + 32768);   // [B]
    float* part  = (float*)(w + (64u << 20) + 65536);   // [6][4][D]

    k_mlp1<<<dim3(4, 4, 6), 256, 0, stream>>>(qtl,
        qpq_w1, qpq_b1, qpq_w2,
        qpk_w1, qpk_b1, qpk_w2,
        qpv_w1, qpv_b1, qpv_w2,
        qimp, part, scl);
    k_mlp2<<<dim3(4, 6), 256, 0, stream>>>(part, qpq_b2, qpk_b2, qpv_b2, emb);
    k_pe<<<4096, 256, 0, stream>>>(x, xpe, xpeb);
    k_wconv<<<dim3(16, 16, 4), 256, 0, stream>>>(Wq, Wk, Wv, Wo, Wt);
    k_qkv<<<dim3(32, 8, 3), 256, 0, stream>>>(xpeb, Wt, bq, bk, bv, emb, scl, Qb, Kb, Vtb);
    k_attn<<<dim3(32, 16), 512, 0, stream>>>(Qb, Kb, Vtb, AOb);
    k_ogemm<<<dim3(32, 8), 256, 0, stream>>>(AOb, Wt + (size_t)3 * D * D, bo, xpe, yb);
    k_ln<<<4096, 256, 0, stream>>>(yb, ln_g, ln_b, (float*)d_out);
}

// Round 4
// 168.862 us; speedup vs baseline: 2.3467x; 1.0776x over previous
//
#include <hip/hip_runtime.h>

#define D 1024
#define T 2048
#define BATCH 2
#define NR 4096
#define NH 16
#define HID 512

typedef unsigned short u16;
typedef unsigned int u32;
typedef unsigned long long u64;
typedef float f32x4 __attribute__((ext_vector_type(4)));
typedef __bf16 bf16x8 __attribute__((ext_vector_type(8)));

// native RNE f32->bf16 (hardware v_cvt)
__device__ __forceinline__ u16 f2bf(float f) {
    union { __bf16 h; u16 u; } c; c.h = (__bf16)f; return c.u;
}

// pack two f32 -> 2xbf16 in one u32 (low = a, high = b). No builtin on gfx950 (m240).
__device__ __forceinline__ u32 cvtpk(float a, float b) {
    u32 r;
    asm("v_cvt_pk_bf16_f32 %0, %1, %2" : "=v"(r) : "v"(a), "v"(b));
    return r;
}

// async global->LDS, 16B per lane. LDS dest is wave-uniform base + lane*16 (linear);
// the read-side XOR swizzle is realized by pre-swizzling the GLOBAL source column.
__device__ __forceinline__ void gload16(const u16* g, u16* l) {
    __builtin_amdgcn_global_load_lds(
        (const __attribute__((address_space(1))) unsigned int*)g,
        (__attribute__((address_space(3))) unsigned int*)l,
        16, 0, 0);
}

// ---------------- quantile MLP stage 1: partial sums + importance scale ----------------
__global__ __launch_bounds__(256) void k_mlp1(const float* __restrict__ qtl,
        const float* __restrict__ w1q, const float* __restrict__ b1q, const float* __restrict__ w2q,
        const float* __restrict__ w1k, const float* __restrict__ b1k, const float* __restrict__ w2k,
        const float* __restrict__ w1v, const float* __restrict__ b1v, const float* __restrict__ w2v,
        const float* __restrict__ qimp, float* __restrict__ part, float* __restrict__ scl)
{
    int dc = blockIdx.x;       // 0..3  (256 d each)
    int jc = blockIdx.y;       // 0..3  (128 j each)
    int wb = blockIdx.z;       // 0..5 : which*2 + b
    int which = wb >> 1, b = wb & 1;
    const float *w1, *b1, *w2;
    if (which == 0)      { w1 = w1q; b1 = b1q; w2 = w2q; }
    else if (which == 1) { w1 = w1k; b1 = b1k; w2 = w2k; }
    else                 { w1 = w1v; b1 = b1v; w2 = w2v; }
    int tid = threadIdx.x;
    __shared__ float h[128];
    if (tid < 128) {
        int j = jc * 128 + tid;
        h[tid] = fmaxf(qtl[b] * w1[j] + b1[j], 0.0f);
    }
    __syncthreads();
    int d = dc * 256 + tid;
    float acc = 0.0f;
    for (int j = 0; j < 128; ++j) acc += h[j] * w2[(size_t)(jc * 128 + j) * D + d];
    part[((size_t)wb * 4 + jc) * D + d] = acc;
    if (dc == 0 && jc == 0 && wb == 0 && tid < BATCH) {
        float mx = qimp[0];
        for (int i = 1; i < 100; ++i) mx = fmaxf(mx, qimp[i]);
        float q = qtl[tid];
        int idx = (int)(q * 100.0f);
        idx = idx < 0 ? 0 : (idx > 99 ? 99 : idx);
        float imp = qimp[idx];
        if (mx > 0.0f) imp /= mx;
        scl[tid] = 1.0f + imp;
    }
}

// ---------------- quantile MLP stage 2: reduce partials + bias ----------------
__global__ __launch_bounds__(256) void k_mlp2(const float* __restrict__ part,
        const float* __restrict__ b2q, const float* __restrict__ b2k, const float* __restrict__ b2v,
        float* __restrict__ embeds)
{
    int dc = blockIdx.x;   // 0..3
    int wb = blockIdx.y;   // 0..5
    int which = wb >> 1;
    const float* b2 = which == 0 ? b2q : which == 1 ? b2k : b2v;
    int d = dc * 256 + threadIdx.x;
    float acc = b2[d];
    #pragma unroll
    for (int jc = 0; jc < 4; ++jc) acc += part[((size_t)wb * 4 + jc) * D + d];
    embeds[(size_t)wb * D + d] = acc;   // [which][b][d]
}

// ---------------- x + sinusoidal PE; fp32 residual copy + bf16 copy ----------------
__global__ __launch_bounds__(256) void k_pe(const float* __restrict__ x,
                                            float* __restrict__ xpe, u16* __restrict__ xpeb)
{
    int idx = (blockIdx.x * 256 + threadIdx.x) * 4;
    int d = idx & (D - 1);
    int t = (idx >> 10) & (T - 1);
    const float KL = -0.0089944731946f;  // -ln(10000)/1024
    float ft = (float)t;
    float dv0 = __expf((float)d * KL);
    float dv1 = __expf((float)(d + 2) * KL);
    float a0 = ft * dv0, a1 = ft * dv1;
    float4 xv = *reinterpret_cast<const float4*>(x + idx);
    float4 r;
    r.x = xv.x + __sinf(a0);
    r.y = xv.y + __cosf(a0);
    r.z = xv.z + __sinf(a1);
    r.w = xv.w + __cosf(a1);
    *reinterpret_cast<float4*>(xpe + idx) = r;
    ushort4 o;
    o.x = f2bf(r.x); o.y = f2bf(r.y); o.z = f2bf(r.z); o.w = f2bf(r.w);
    *reinterpret_cast<ushort4*>(xpeb + idx) = o;
}

// ---------------- weight transpose + bf16 convert: Wt[n][k] = bf16(W[k][n]) ----------------
__global__ __launch_bounds__(256) void k_wconv(const float* __restrict__ Wq, const float* __restrict__ Wk,
                                               const float* __restrict__ Wv, const float* __restrict__ Wo,
                                               u16* __restrict__ Wt)
{
    __shared__ float tile[64][65];
    int z = blockIdx.z;
    const float* W = z == 0 ? Wq : z == 1 ? Wk : z == 2 ? Wv : Wo;
    u16* out = Wt + (size_t)z * D * D;
    int n0 = blockIdx.x * 64, k0 = blockIdx.y * 64;
    int r = threadIdx.x >> 4;
    int c4 = (threadIdx.x & 15) * 4;
    #pragma unroll
    for (int rr = 0; rr < 64; rr += 16) {
        float4 v = *reinterpret_cast<const float4*>(W + (size_t)(k0 + r + rr) * D + n0 + c4);
        tile[r + rr][c4 + 0] = v.x; tile[r + rr][c4 + 1] = v.y;
        tile[r + rr][c4 + 2] = v.z; tile[r + rr][c4 + 3] = v.w;
    }
    __syncthreads();
    #pragma unroll
    for (int rr = 0; rr < 64; rr += 16) {
        ushort4 o;
        o.x = f2bf(tile[c4 + 0][r + rr]);
        o.y = f2bf(tile[c4 + 1][r + rr]);
        o.z = f2bf(tile[c4 + 2][r + rr]);
        o.w = f2bf(tile[c4 + 3][r + rr]);
        *reinterpret_cast<ushort4*>(out + (size_t)(n0 + r + rr) * D + k0 + c4) = o;
    }
}

// ---------------- shared 128x128 bf16 MFMA GEMM core (K=1024, BK=64, m97 structure) ----------------
// A[m][k] row-major bf16, B = Wt[n][k] row-major bf16 (i.e. B^T layout).
__device__ __forceinline__ void gemm128(const u16* __restrict__ Ag, const u16* __restrict__ Bg,
                                        int m0, int n0, f32x4 acc[4][4])
{
    __shared__ u16 As[128 * 64];
    __shared__ u16 Bs[128 * 64];
    const int tid = threadIdx.x;
    const int lane = tid & 63, wave = tid >> 6;
    const int wr = wave >> 1, wc = wave & 1;
    #pragma unroll
    for (int i = 0; i < 4; ++i)
        #pragma unroll
        for (int j = 0; j < 4; ++j)
            #pragma unroll
            for (int e = 0; e < 4; ++e) acc[i][j][e] = 0.0f;

    for (int kt = 0; kt < 16; ++kt) {
        __syncthreads();   // prev tile fully consumed by all waves
        #pragma unroll
        for (int c = 0; c < 4; ++c) {
            int ci = c * 256 + tid;
            int row = ci >> 3;
            int sl = (ci & 7) ^ (row & 7);   // pre-swizzled global column slot
            gload16(Ag + (size_t)(m0 + row) * D + kt * 64 + sl * 8, As + (size_t)ci * 8);
            gload16(Bg + (size_t)(n0 + row) * D + kt * 64 + sl * 8, Bs + (size_t)ci * 8);
        }
        __syncthreads();   // drains vmcnt(0): staged data visible to all
        #pragma unroll
        for (int ks = 0; ks < 2; ++ks) {
            bf16x8 af[4], bfr[4];
            #pragma unroll
            for (int i = 0; i < 4; ++i) {
                int ra = wr * 64 + i * 16 + (lane & 15);
                int sa = ((ks * 4 + (lane >> 4)) ^ (ra & 7));
                af[i] = *reinterpret_cast<const bf16x8*>((const char*)As + ra * 128 + sa * 16);
                int rb = wc * 64 + i * 16 + (lane & 15);
                int sb = ((ks * 4 + (lane >> 4)) ^ (rb & 7));
                bfr[i] = *reinterpret_cast<const bf16x8*>((const char*)Bs + rb * 128 + sb * 16);
            }
            #pragma unroll
            for (int i = 0; i < 4; ++i)
                #pragma unroll
                for (int j = 0; j < 4; ++j)
                    acc[i][j] = __builtin_amdgcn_mfma_f32_16x16x32_bf16(af[i], bfr[j], acc[i][j], 0, 0, 0);
        }
    }
}

// ---------------- Q/K/V projections (Q pre-scaled by scl[b]*log2(e)/sqrt(dk)) ----------------
__global__ __launch_bounds__(256, 2)
void k_qkv(const u16* __restrict__ A, const u16* __restrict__ Wt,
           const float* __restrict__ bq, const float* __restrict__ bk, const float* __restrict__ bv,
           const float* __restrict__ embeds, const float* __restrict__ scl,
           u16* __restrict__ Qo, u16* __restrict__ Ko, u16* __restrict__ Vt)
{
    int which = blockIdx.z;
    const u16* Bg = Wt + (size_t)which * D * D;
    const float* bias = which == 0 ? bq : which == 1 ? bk : bv;
    const float* emb = embeds + which * (BATCH * D);
    int m0 = blockIdx.x * 128, n0 = blockIdx.y * 128;
    f32x4 acc[4][4];
    gemm128(A, Bg, m0, n0, acc);
    int lane = threadIdx.x & 63, wave = threadIdx.x >> 6;
    int wr = wave >> 1, wc = wave & 1;
    int rowbase = m0 + wr * 64 + ((lane >> 4) << 2);
    int colbase = n0 + wc * 64 + (lane & 15);
    if (which < 2) {
        u16* Out = which == 0 ? Qo : Ko;
        float sc0 = 1.0f, sc1 = 1.0f;
        if (which == 0) {
            sc0 = scl[0] * 0.125f * 1.44269504f;   // fold 1/sqrt(dk) * temp-scale * log2(e)
            sc1 = scl[1] * 0.125f * 1.44269504f;
        }
        #pragma unroll
        for (int j = 0; j < 4; ++j) {
            int c = colbase + j * 16;
            float add0 = bias[c] + emb[c];
            float add1 = bias[c] + emb[D + c];
            #pragma unroll
            for (int i = 0; i < 4; ++i) {
                int rb = rowbase + i * 16;
                #pragma unroll
                for (int jj = 0; jj < 4; ++jj) {
                    int r = rb + jj;
                    float v = (r >> 11) ? (acc[i][j][jj] + add1) * sc1
                                        : (acc[i][j][jj] + add0) * sc0;
                    Out[(size_t)r * D + c] = f2bf(v);
                }
            }
        }
    } else {
        // V stored transposed per-head: Vt[((b*NH + h)*64 + cc)][t]
        #pragma unroll
        for (int j = 0; j < 4; ++j) {
            int c = colbase + j * 16;
            int hh = c >> 6, cc = c & 63;
            float add0 = bias[c] + emb[c];
            float add1 = bias[c] + emb[D + c];
            #pragma unroll
            for (int i = 0; i < 4; ++i) {
                int rb = rowbase + i * 16;
                int bb = rb >> 11;
                int t = rb & (T - 1);
                float add = bb ? add1 : add0;
                ushort4 o;
                o.x = f2bf(acc[i][j][0] + add);
                o.y = f2bf(acc[i][j][1] + add);
                o.z = f2bf(acc[i][j][2] + add);
                o.w = f2bf(acc[i][j][3] + add);
                *reinterpret_cast<ushort4*>(Vt + ((size_t)((bb * NH + hh) * 64 + cc)) * T + t) = o;
            }
        }
    }
}

// ---------------- flash attention: QBLK=128 (8 waves), KVBLK=128, swapped QK^T ----------------
// S^T = mfma(K,Q): lane owns full S-row for q=lane&15 -> lane-local softmax, P stays in regs.
// K/V double-buffered; stage(t+1) issued BEFORE compute(t) (T3-min 2-phase).
__global__ __launch_bounds__(512, 4)
void k_attn(const u16* __restrict__ Q, const u16* __restrict__ K, const u16* __restrict__ Vt,
            u16* __restrict__ AO)
{
    __shared__ u16 Ks[2][128 * 64];    // [t=128][d=64], 8x16B slots/row, slot^=(t&7)
    __shared__ u16 Vs[2][64 * 128];    // [d=64][t=128], 16x16B slots/row, slot^=(d&7)
    int bh = blockIdx.x;
    int b = bh >> 4, hh = bh & 15;
    int q0 = blockIdx.y * 128;
    int tid = threadIdx.x;
    int lane = tid & 63, wave = tid >> 6, g = lane >> 4;

    bf16x8 qf[2];
    {
        size_t off = (size_t)(b * T + q0 + wave * 16 + (lane & 15)) * D + hh * 64 + (g << 3);
        qf[0] = *reinterpret_cast<const bf16x8*>(Q + off);
        qf[1] = *reinterpret_cast<const bf16x8*>(Q + off + 32);
    }

    f32x4 o[4];
    #pragma unroll
    for (int j = 0; j < 4; ++j)
        #pragma unroll
        for (int e = 0; e < 4; ++e) o[j][e] = 0.0f;
    float m_run = -1e30f, l_run = 0.0f;   // stats for q = lane&15 (log2 domain)

    // prologue: stage tile 0 into buffer 0
    #pragma unroll
    for (int c = 0; c < 2; ++c) {
        int ci = c * 512 + tid;
        int row = ci >> 3;
        int sl = (ci & 7) ^ (row & 7);
        gload16(K + (size_t)(b * T + row) * D + hh * 64 + sl * 8, Ks[0] + (size_t)ci * 8);
        int rowv = ci >> 4;
        int slv = (ci & 15) ^ (rowv & 7);
        gload16(Vt + (size_t)(bh * 64 + rowv) * T + slv * 8, Vs[0] + (size_t)ci * 8);
    }
    __syncthreads();   // vmcnt(0)+barrier: tile 0 visible

    for (int kt = 0; kt < 16; ++kt) {
        int cur = kt & 1;
        // issue next tile's loads (fly under this tile's compute)
        if (kt < 15) {
            int t0 = (kt + 1) * 128;
            #pragma unroll
            for (int c = 0; c < 2; ++c) {
                int ci = c * 512 + tid;
                int row = ci >> 3;
                int sl = (ci & 7) ^ (row & 7);
                gload16(K + (size_t)(b * T + t0 + row) * D + hh * 64 + sl * 8, Ks[cur ^ 1] + (size_t)ci * 8);
                int rowv = ci >> 4;
                int slv = (ci & 15) ^ (rowv & 7);
                gload16(Vt + (size_t)(bh * 64 + rowv) * T + t0 + slv * 8, Vs[cur ^ 1] + (size_t)ci * 8);
            }
        }
        const char* Ksc = (const char*)Ks[cur];
        const char* Vsc = (const char*)Vs[cur];
        // S^T = mfma(K, Q): s[ni][r] = S[q=lane&15][k = ni*16 + g*4 + r]  (log2 domain)
        f32x4 s[8];
        #pragma unroll
        for (int ni = 0; ni < 8; ++ni)
            #pragma unroll
            for (int e = 0; e < 4; ++e) s[ni][e] = 0.0f;
        __builtin_amdgcn_s_setprio(1);
        #pragma unroll
        for (int ks = 0; ks < 2; ++ks)
            #pragma unroll
            for (int ni = 0; ni < 8; ++ni) {
                int rk = ni * 16 + (lane & 15);
                int sp = (ks * 4 + g) ^ (rk & 7);
                bf16x8 kf = *reinterpret_cast<const bf16x8*>(Ksc + rk * 128 + sp * 16);
                s[ni] = __builtin_amdgcn_mfma_f32_16x16x32_bf16(kf, qf[ks], s[ni], 0, 0, 0);
            }
        __builtin_amdgcn_s_setprio(0);
        // lane-local softmax over 32 values + 2-shfl cross-group combine
        float mt = s[0][0];
        #pragma unroll
        for (int ni = 0; ni < 8; ++ni)
            #pragma unroll
            for (int e = 0; e < 4; ++e) mt = fmaxf(mt, s[ni][e]);
        mt = fmaxf(mt, __shfl_xor(mt, 16, 64));
        mt = fmaxf(mt, __shfl_xor(mt, 32, 64));
        bool skip = __all((int)(mt <= m_run + 11.0f));   // defer-max, 2^11 headroom
        float corr = 1.0f;
        if (!skip) {
            float mn = fmaxf(m_run, mt);
            corr = __builtin_exp2f(m_run - mn);
            m_run = mn;
        }
        float psum = 0.0f;
        #pragma unroll
        for (int ni = 0; ni < 8; ++ni)
            #pragma unroll
            for (int e = 0; e < 4; ++e) {
                float p = __builtin_exp2f(s[ni][e] - m_run);
                s[ni][e] = p;
                psum += p;
            }
        psum += __shfl_xor(psum, 16, 64);
        psum += __shfl_xor(psum, 32, 64);
        if (!skip) {
            l_run = l_run * corr + psum;
            // redistribute corr from q=lane&15 domain to o's q=(g*4+jr) domain
            float c4[4];
            #pragma unroll
            for (int jr = 0; jr < 4; ++jr)
                c4[jr] = __shfl(corr, (lane & 48) | (g << 2) | jr, 64);
            #pragma unroll
            for (int j = 0; j < 4; ++j)
                #pragma unroll
                for (int jr = 0; jr < 4; ++jr) o[j][jr] *= c4[jr];
        } else {
            l_run += psum;
        }
        // O += P V with register-local P (kappa-permuted operands; mfma sum is order-free)
        __builtin_amdgcn_s_setprio(1);
        #pragma unroll
        for (int kb = 0; kb < 4; ++kb) {
            union { bf16x8 v; u32 w[4]; } pa;
            pa.w[0] = cvtpk(s[2 * kb][0], s[2 * kb][1]);
            pa.w[1] = cvtpk(s[2 * kb][2], s[2 * kb][3]);
            pa.w[2] = cvtpk(s[2 * kb + 1][0], s[2 * kb + 1][1]);
            pa.w[3] = cvtpk(s[2 * kb + 1][2], s[2 * kb + 1][3]);
            #pragma unroll
            for (int j = 0; j < 4; ++j) {
                int rv = j * 16 + (lane & 15);
                int xm = rv & 7;
                const char* vb = Vsc + rv * 256 + (g & 1) * 8;
                union { bf16x8 v; u64 d[2]; } vf;
                vf.d[0] = *reinterpret_cast<const u64*>(vb + (((4 * kb + (g >> 1)) ^ xm) << 4));
                vf.d[1] = *reinterpret_cast<const u64*>(vb + (((4 * kb + (g >> 1) + 2) ^ xm) << 4));
                o[j] = __builtin_amdgcn_mfma_f32_16x16x32_bf16(pa.v, vf.v, o[j], 0, 0, 0);
            }
        }
        __builtin_amdgcn_s_setprio(0);
        __syncthreads();   // drains vmcnt(0): next tile staged & visible; cur buffer free
    }
    // epilogue: normalize; redistribute 1/l from q=lane&15 to q=(g*4+jr)
    float linv = 1.0f / l_run;
    float l4[4];
    #pragma unroll
    for (int jr = 0; jr < 4; ++jr)
        l4[jr] = __shfl(linv, (lane & 48) | (g << 2) | jr, 64);
    #pragma unroll
    for (int j = 0; j < 4; ++j)
        #pragma unroll
        for (int jr = 0; jr < 4; ++jr) {
            size_t off = (size_t)(b * T + q0 + wave * 16 + (g << 2) + jr) * D + hh * 64 + j * 16 + (lane & 15);
            AO[off] = f2bf(o[j][jr] * l4[jr]);
        }
}

// ---------------- output projection + bias + residual ----------------
__global__ __launch_bounds__(256, 2)
void k_ogemm(const u16* __restrict__ A, const u16* __restrict__ Wt,
             const float* __restrict__ bo, const float* __restrict__ xpe,
             float* __restrict__ y)
{
    int m0 = blockIdx.x * 128, n0 = blockIdx.y * 128;
    f32x4 acc[4][4];
    gemm128(A, Wt, m0, n0, acc);
    int lane = threadIdx.x & 63, wave = threadIdx.x >> 6;
    int wr = wave >> 1, wc = wave & 1;
    int rowbase = m0 + wr * 64 + ((lane >> 4) << 2);
    int colbase = n0 + wc * 64 + (lane & 15);
    #pragma unroll
    for (int j = 0; j < 4; ++j) {
        int c = colbase + j * 16;
        float bc = bo[c];
        #pragma unroll
        for (int i = 0; i < 4; ++i) {
            #pragma unroll
            for (int jj = 0; jj < 4; ++jj) {
                int r = rowbase + i * 16 + jj;
                y[(size_t)r * D + c] = acc[i][j][jj] + bc + xpe[(size_t)r * D + c];
            }
        }
    }
}

// ---------------- LayerNorm ----------------
__global__ __launch_bounds__(256) void k_ln(const float* __restrict__ y, const float* __restrict__ g,
                                            const float* __restrict__ bb, float* __restrict__ out)
{
    int row = blockIdx.x;
    int tid = threadIdx.x;
    const float* yr = y + (size_t)row * D;
    float4 v = *reinterpret_cast<const float4*>(yr + tid * 4);
    float s = v.x + v.y + v.z + v.w;
    float s2 = v.x * v.x + v.y * v.y + v.z * v.z + v.w * v.w;
    #pragma unroll
    for (int off = 1; off < 64; off <<= 1) {
        s += __shfl_xor(s, off, 64);
        s2 += __shfl_xor(s2, off, 64);
    }
    __shared__ float red[8];
    int wave = tid >> 6, lane = tid & 63;
    if (lane == 0) { red[wave] = s; red[4 + wave] = s2; }
    __syncthreads();
    s = red[0] + red[1] + red[2] + red[3];
    s2 = red[4] + red[5] + red[6] + red[7];
    float mu = s * (1.0f / 1024.0f);
    float var = s2 * (1.0f / 1024.0f) - mu * mu;
    float rstd = rsqrtf(var + 1e-5f);
    float4 gv = *reinterpret_cast<const float4*>(g + tid * 4);
    float4 bv = *reinterpret_cast<const float4*>(bb + tid * 4);
    float4 o;
    o.x = (v.x - mu) * rstd * gv.x + bv.x;
    o.y = (v.y - mu) * rstd * gv.y + bv.y;
    o.z = (v.z - mu) * rstd * gv.z + bv.z;
    o.w = (v.w - mu) * rstd * gv.w + bv.w;
    *reinterpret_cast<float4*>(out + (size_t)row * D + tid * 4) = o;
}

extern "C" void kernel_launch(void* const* d_in, const int* in_sizes, int n_in,
                              void* d_out, int out_size, void* d_ws, size_t ws_size,
                              hipStream_t stream)
{
    const float* x    = (const float*)d_in[0];
    const float* qtl  = (const float*)d_in[1];
    const float* qimp = (const float*)d_in[2];
    const float* Wq = (const float*)d_in[3];
    const float* bq = (const float*)d_in[4];
    const float* Wk = (const float*)d_in[5];
    const float* bk = (const float*)d_in[6];
    const float* Wv = (const float*)d_in[7];
    const float* bv = (const float*)d_in[8];
    const float* Wo = (const float*)d_in[9];
    const float* bo = (const float*)d_in[10];
    const float* qpq_w1 = (const float*)d_in[11];
    const float* qpq_b1 = (const float*)d_in[12];
    const float* qpq_w2 = (const float*)d_in[13];
    const float* qpq_b2 = (const float*)d_in[14];
    const float* qpk_w1 = (const float*)d_in[15];
    const float* qpk_b1 = (const float*)d_in[16];
    const float* qpk_w2 = (const float*)d_in[17];
    const float* qpk_b2 = (const float*)d_in[18];
    const float* qpv_w1 = (const float*)d_in[19];
    const float* qpv_b1 = (const float*)d_in[20];
    const float* qpv_w2 = (const float*)d_in[21];
    const float* qpv_b2 = (const float*)d_in[22];
    const float* ln_g = (const float*)d_in[23];
    const float* ln_b = (const float*)d_in[24];
    (void)in_sizes; (void)n_in; (void)out_size; (void)ws_size;

    char* w = (char*)d_ws;
    float* xpe   = (float*)(w);                         // 16 MB fp32 residual
    u16* xpeb    = (u16*)(w + (16u << 20));             // 8 MB bf16
    u16* Wt      = (u16*)(w + (24u << 20));             // 8 MB: Wq,Wk,Wv,Wo transposed bf16
    u16* Qb      = (u16*)(w + (32u << 20));             // 8 MB bf16 [NR][D]
    u16* Kb      = (u16*)(w + (40u << 20));             // 8 MB bf16 [NR][D]
    u16* Vtb     = (u16*)(w + (48u << 20));             // 8 MB bf16 [B*NH*64][T]
    u16* AOb     = (u16*)(w + (56u << 20));             // 8 MB bf16 [NR][D]
    float* yb    = (float*)(w + (32u << 20));           // 16 MB fp32, aliases Qb/Kb (dead then)
    float* emb   = (float*)(w + (64u << 20));           // [3][B][D]
    float* scl   = (float*)(w + (64u << 20) + 32768);   // [B]
    float* part  = (float*)(w + (64u << 20) + 65536);   // [6][4][D]

    k_mlp1<<<dim3(4, 4, 6), 256, 0, stream>>>(qtl,
        qpq_w1, qpq_b1, qpq_w2,
        qpk_w1, qpk_b1, qpk_w2,
        qpv_w1, qpv_b1, qpv_w2,
        qimp, part, scl);
    k_mlp2<<<dim3(4, 6), 256, 0, stream>>>(part, qpq_b2, qpk_b2, qpv_b2, emb);
    k_pe<<<4096, 256, 0, stream>>>(x, xpe, xpeb);
    k_wconv<<<dim3(16, 16, 4), 256, 0, stream>>>(Wq, Wk, Wv, Wo, Wt);
    k_qkv<<<dim3(32, 8, 3), 256, 0, stream>>>(xpeb, Wt, bq, bk, bv, emb, scl, Qb, Kb, Vtb);
    k_attn<<<dim3(32, 16), 512, 0, stream>>>(Qb, Kb, Vtb, AOb);
    k_ogemm<<<dim3(32, 8), 256, 0, stream>>>(AOb, Wt + (size_t)3 * D * D, bo, xpe, yb);
    k_ln<<<4096, 256, 0, stream>>>(yb, ln_g, ln_b, (float*)d_out);
}

// Round 5
// 162.442 us; speedup vs baseline: 2.4394x; 1.0395x over previous
//
#include <hip/hip_runtime.h>

#define D 1024
#define T 2048
#define BATCH 2
#define NR 4096
#define NH 16
#define HID 512

typedef unsigned short u16;
typedef unsigned int u32;
typedef unsigned long long u64;
typedef float f32x4 __attribute__((ext_vector_type(4)));
typedef float f32x16 __attribute__((ext_vector_type(16)));
typedef __bf16 bf16x8 __attribute__((ext_vector_type(8)));

// native RNE f32->bf16 (hardware v_cvt)
__device__ __forceinline__ u16 f2bf(float f) {
    union { __bf16 h; u16 u; } c; c.h = (__bf16)f; return c.u;
}

// pack two f32 -> 2xbf16 in one u32 (low = a, high = b). No builtin on gfx950 (m240).
__device__ __forceinline__ u32 cvtpk(float a, float b) {
    u32 r;
    asm("v_cvt_pk_bf16_f32 %0, %1, %2" : "=v"(r) : "v"(a), "v"(b));
    return r;
}

// v_permlane32_swap_b32: x[32..63] <-> y[0..31].  After: x = [x_lo | y_lo-from-partner],
// y = [x_hi-from-partner | y_hi].
__device__ __forceinline__ void plswap(u32& x, u32& y) {
    asm volatile("v_permlane32_swap_b32 %0, %1" : "+v"(x), "+v"(y));
}

// async global->LDS, 16B per lane. LDS dest is wave-uniform base + lane*16 (linear);
// the read-side XOR swizzle is realized by pre-swizzling the GLOBAL source column.
__device__ __forceinline__ void gload16(const u16* g, u16* l) {
    __builtin_amdgcn_global_load_lds(
        (const __attribute__((address_space(1))) unsigned int*)g,
        (__attribute__((address_space(3))) unsigned int*)l,
        16, 0, 0);
}

// ---------------- quantile MLP stage 1: partial sums + importance scale ----------------
__global__ __launch_bounds__(256) void k_mlp1(const float* __restrict__ qtl,
        const float* __restrict__ w1q, const float* __restrict__ b1q, const float* __restrict__ w2q,
        const float* __restrict__ w1k, const float* __restrict__ b1k, const float* __restrict__ w2k,
        const float* __restrict__ w1v, const float* __restrict__ b1v, const float* __restrict__ w2v,
        const float* __restrict__ qimp, float* __restrict__ part, float* __restrict__ scl)
{
    int dc = blockIdx.x;       // 0..3  (256 d each)
    int jc = blockIdx.y;       // 0..3  (128 j each)
    int wb = blockIdx.z;       // 0..5 : which*2 + b
    int which = wb >> 1, b = wb & 1;
    const float *w1, *b1, *w2;
    if (which == 0)      { w1 = w1q; b1 = b1q; w2 = w2q; }
    else if (which == 1) { w1 = w1k; b1 = b1k; w2 = w2k; }
    else                 { w1 = w1v; b1 = b1v; w2 = w2v; }
    int tid = threadIdx.x;
    __shared__ float h[128];
    if (tid < 128) {
        int j = jc * 128 + tid;
        h[tid] = fmaxf(qtl[b] * w1[j] + b1[j], 0.0f);
    }
    __syncthreads();
    int d = dc * 256 + tid;
    float acc = 0.0f;
    for (int j = 0; j < 128; ++j) acc += h[j] * w2[(size_t)(jc * 128 + j) * D + d];
    part[((size_t)wb * 4 + jc) * D + d] = acc;
    if (dc == 0 && jc == 0 && wb == 0 && tid < BATCH) {
        float mx = qimp[0];
        for (int i = 1; i < 100; ++i) mx = fmaxf(mx, qimp[i]);
        float q = qtl[tid];
        int idx = (int)(q * 100.0f);
        idx = idx < 0 ? 0 : (idx > 99 ? 99 : idx);
        float imp = qimp[idx];
        if (mx > 0.0f) imp /= mx;
        scl[tid] = 1.0f + imp;
    }
}

// ---------------- quantile MLP stage 2: reduce partials + bias ----------------
__global__ __launch_bounds__(256) void k_mlp2(const float* __restrict__ part,
        const float* __restrict__ b2q, const float* __restrict__ b2k, const float* __restrict__ b2v,
        float* __restrict__ embeds)
{
    int dc = blockIdx.x;   // 0..3
    int wb = blockIdx.y;   // 0..5
    int which = wb >> 1;
    const float* b2 = which == 0 ? b2q : which == 1 ? b2k : b2v;
    int d = dc * 256 + threadIdx.x;
    float acc = b2[d];
    #pragma unroll
    for (int jc = 0; jc < 4; ++jc) acc += part[((size_t)wb * 4 + jc) * D + d];
    embeds[(size_t)wb * D + d] = acc;   // [which][b][d]
}

// ---------------- x + sinusoidal PE; fp32 residual copy + bf16 copy ----------------
__global__ __launch_bounds__(256) void k_pe(const float* __restrict__ x,
                                            float* __restrict__ xpe, u16* __restrict__ xpeb)
{
    int idx = (blockIdx.x * 256 + threadIdx.x) * 4;
    int d = idx & (D - 1);
    int t = (idx >> 10) & (T - 1);
    const float KL = -0.0089944731946f;  // -ln(10000)/1024
    float ft = (float)t;
    float dv0 = __expf((float)d * KL);
    float dv1 = __expf((float)(d + 2) * KL);
    float a0 = ft * dv0, a1 = ft * dv1;
    float4 xv = *reinterpret_cast<const float4*>(x + idx);
    float4 r;
    r.x = xv.x + __sinf(a0);
    r.y = xv.y + __cosf(a0);
    r.z = xv.z + __sinf(a1);
    r.w = xv.w + __cosf(a1);
    *reinterpret_cast<float4*>(xpe + idx) = r;
    ushort4 o;
    o.x = f2bf(r.x); o.y = f2bf(r.y); o.z = f2bf(r.z); o.w = f2bf(r.w);
    *reinterpret_cast<ushort4*>(xpeb + idx) = o;
}

// ---------------- weight transpose + bf16 convert: Wt[n][k] = bf16(W[k][n]) ----------------
__global__ __launch_bounds__(256) void k_wconv(const float* __restrict__ Wq, const float* __restrict__ Wk,
                                               const float* __restrict__ Wv, const float* __restrict__ Wo,
                                               u16* __restrict__ Wt)
{
    __shared__ float tile[64][65];
    int z = blockIdx.z;
    const float* W = z == 0 ? Wq : z == 1 ? Wk : z == 2 ? Wv : Wo;
    u16* out = Wt + (size_t)z * D * D;
    int n0 = blockIdx.x * 64, k0 = blockIdx.y * 64;
    int r = threadIdx.x >> 4;
    int c4 = (threadIdx.x & 15) * 4;
    #pragma unroll
    for (int rr = 0; rr < 64; rr += 16) {
        float4 v = *reinterpret_cast<const float4*>(W + (size_t)(k0 + r + rr) * D + n0 + c4);
        tile[r + rr][c4 + 0] = v.x; tile[r + rr][c4 + 1] = v.y;
        tile[r + rr][c4 + 2] = v.z; tile[r + rr][c4 + 3] = v.w;
    }
    __syncthreads();
    #pragma unroll
    for (int rr = 0; rr < 64; rr += 16) {
        ushort4 o;
        o.x = f2bf(tile[c4 + 0][r + rr]);
        o.y = f2bf(tile[c4 + 1][r + rr]);
        o.z = f2bf(tile[c4 + 2][r + rr]);
        o.w = f2bf(tile[c4 + 3][r + rr]);
        *reinterpret_cast<ushort4*>(out + (size_t)(n0 + r + rr) * D + k0 + c4) = o;
    }
}

// ---------------- shared 128x128 bf16 MFMA GEMM core (K=1024, BK=64, m97 structure) ----------------
// A[m][k] row-major bf16, B = Wt[n][k] row-major bf16 (i.e. B^T layout).
__device__ __forceinline__ void gemm128(const u16* __restrict__ Ag, const u16* __restrict__ Bg,
                                        int m0, int n0, f32x4 acc[4][4])
{
    __shared__ u16 As[128 * 64];
    __shared__ u16 Bs[128 * 64];
    const int tid = threadIdx.x;
    const int lane = tid & 63, wave = tid >> 6;
    const int wr = wave >> 1, wc = wave & 1;
    #pragma unroll
    for (int i = 0; i < 4; ++i)
        #pragma unroll
        for (int j = 0; j < 4; ++j)
            #pragma unroll
            for (int e = 0; e < 4; ++e) acc[i][j][e] = 0.0f;

    for (int kt = 0; kt < 16; ++kt) {
        __syncthreads();   // prev tile fully consumed by all waves
        #pragma unroll
        for (int c = 0; c < 4; ++c) {
            int ci = c * 256 + tid;
            int row = ci >> 3;
            int sl = (ci & 7) ^ (row & 7);   // pre-swizzled global column slot
            gload16(Ag + (size_t)(m0 + row) * D + kt * 64 + sl * 8, As + (size_t)ci * 8);
            gload16(Bg + (size_t)(n0 + row) * D + kt * 64 + sl * 8, Bs + (size_t)ci * 8);
        }
        __syncthreads();   // drains vmcnt(0): staged data visible to all
        #pragma unroll
        for (int ks = 0; ks < 2; ++ks) {
            bf16x8 af[4], bfr[4];
            #pragma unroll
            for (int i = 0; i < 4; ++i) {
                int ra = wr * 64 + i * 16 + (lane & 15);
                int sa = ((ks * 4 + (lane >> 4)) ^ (ra & 7));
                af[i] = *reinterpret_cast<const bf16x8*>((const char*)As + ra * 128 + sa * 16);
                int rb = wc * 64 + i * 16 + (lane & 15);
                int sb = ((ks * 4 + (lane >> 4)) ^ (rb & 7));
                bfr[i] = *reinterpret_cast<const bf16x8*>((const char*)Bs + rb * 128 + sb * 16);
            }
            #pragma unroll
            for (int i = 0; i < 4; ++i)
                #pragma unroll
                for (int j = 0; j < 4; ++j)
                    acc[i][j] = __builtin_amdgcn_mfma_f32_16x16x32_bf16(af[i], bfr[j], acc[i][j], 0, 0, 0);
        }
    }
}

// ---------------- Q/K/V projections (Q pre-scaled by scl[b]*log2(e)/sqrt(dk)) ----------------
__global__ __launch_bounds__(256, 2)
void k_qkv(const u16* __restrict__ A, const u16* __restrict__ Wt,
           const float* __restrict__ bq, const float* __restrict__ bk, const float* __restrict__ bv,
           const float* __restrict__ embeds, const float* __restrict__ scl,
           u16* __restrict__ Qo, u16* __restrict__ Ko, u16* __restrict__ Vt)
{
    int which = blockIdx.z;
    const u16* Bg = Wt + (size_t)which * D * D;
    const float* bias = which == 0 ? bq : which == 1 ? bk : bv;
    const float* emb = embeds + which * (BATCH * D);
    int m0 = blockIdx.x * 128, n0 = blockIdx.y * 128;
    f32x4 acc[4][4];
    gemm128(A, Bg, m0, n0, acc);
    int lane = threadIdx.x & 63, wave = threadIdx.x >> 6;
    int wr = wave >> 1, wc = wave & 1;
    int rowbase = m0 + wr * 64 + ((lane >> 4) << 2);
    int colbase = n0 + wc * 64 + (lane & 15);
    if (which < 2) {
        u16* Out = which == 0 ? Qo : Ko;
        float sc0 = 1.0f, sc1 = 1.0f;
        if (which == 0) {
            sc0 = scl[0] * 0.125f * 1.44269504f;   // fold 1/sqrt(dk) * temp-scale * log2(e)
            sc1 = scl[1] * 0.125f * 1.44269504f;
        }
        #pragma unroll
        for (int j = 0; j < 4; ++j) {
            int c = colbase + j * 16;
            float add0 = bias[c] + emb[c];
            float add1 = bias[c] + emb[D + c];
            #pragma unroll
            for (int i = 0; i < 4; ++i) {
                int rb = rowbase + i * 16;
                #pragma unroll
                for (int jj = 0; jj < 4; ++jj) {
                    int r = rb + jj;
                    float v = (r >> 11) ? (acc[i][j][jj] + add1) * sc1
                                        : (acc[i][j][jj] + add0) * sc0;
                    Out[(size_t)r * D + c] = f2bf(v);
                }
            }
        }
    } else {
        // V stored transposed per-head: Vt[((b*NH + h)*64 + cc)][t]
        #pragma unroll
        for (int j = 0; j < 4; ++j) {
            int c = colbase + j * 16;
            int hh = c >> 6, cc = c & 63;
            float add0 = bias[c] + emb[c];
            float add1 = bias[c] + emb[D + c];
            #pragma unroll
            for (int i = 0; i < 4; ++i) {
                int rb = rowbase + i * 16;
                int bb = rb >> 11;
                int t = rb & (T - 1);
                float add = bb ? add1 : add0;
                ushort4 o;
                o.x = f2bf(acc[i][j][0] + add);
                o.y = f2bf(acc[i][j][1] + add);
                o.z = f2bf(acc[i][j][2] + add);
                o.w = f2bf(acc[i][j][3] + add);
                *reinterpret_cast<ushort4*>(Vt + ((size_t)((bb * NH + hh) * 64 + cc)) * T + t) = o;
            }
        }
    }
}

// ---------------- flash attention: QBLK=128 (4 waves x 32q), KVBLK=128, 32x32x16 MFMA ----------------
// Swapped QK^T = mfma(K, Q): lane owns q = lane&31; S^T reg k-map = (reg&3)+8*(reg>>2)+4*(lane>>5).
// P stays in regs: cvt_pk pairs + v_permlane32_swap build PV A-fragments (T12).
// K/V double-buffered; stage(t+1) issued BEFORE compute(t).
__global__ __launch_bounds__(256, 2)
void k_attn(const u16* __restrict__ Q, const u16* __restrict__ K, const u16* __restrict__ Vt,
            u16* __restrict__ AO)
{
    __shared__ u16 Ks[2][128 * 64];    // [t=128][d=64], 8x16B slots/row, slot ^= (t&7)
    __shared__ u16 Vs[2][64 * 128];    // [d=64][t=128], 16x16B slots/row, slot ^= (d&7)
    int bh = blockIdx.x;
    int b = bh >> 4, hh = bh & 15;
    int q0 = blockIdx.y * 128;
    int tid = threadIdx.x;
    int lane = tid & 63, w = tid >> 6;
    int q31 = lane & 31, h = lane >> 5;

    // Q fragments (B-operand of mfma(K,Q)): qf[ds] = Q[qrow][hh*64 + ds*16 + h*8 .. +7]
    bf16x8 qf[4];
    {
        const u16* qp = Q + (size_t)(b * T + q0 + w * 32 + q31) * D + hh * 64 + h * 8;
        #pragma unroll
        for (int ds = 0; ds < 4; ++ds)
            qf[ds] = *reinterpret_cast<const bf16x8*>(qp + ds * 16);
    }

    f32x16 o0, o1;                     // O[q(reg-map)][d = dt*32 + q31]
    #pragma unroll
    for (int e = 0; e < 16; ++e) { o0[e] = 0.0f; o1[e] = 0.0f; }
    float m_run = -1e30f, l_run = 0.0f;  // stats for q = q31 (log2 domain)

    // prologue: stage tile 0 into buffer 0
    #pragma unroll
    for (int c = 0; c < 4; ++c) {
        int ci = c * 256 + tid;
        int row = ci >> 3;
        int sl = (ci & 7) ^ (row & 7);
        gload16(K + (size_t)(b * T + row) * D + hh * 64 + sl * 8, Ks[0] + (size_t)ci * 8);
        int rv = ci >> 4;
        int sv = (ci & 15) ^ (rv & 7);
        gload16(Vt + (size_t)(bh * 64 + rv) * T + sv * 8, Vs[0] + (size_t)ci * 8);
    }
    __syncthreads();   // vmcnt(0)+barrier: tile 0 visible

    for (int kt = 0; kt < 16; ++kt) {
        int cur = kt & 1;
        if (kt < 15) {   // issue next tile's loads under this tile's compute
            int t0 = (kt + 1) * 128;
            #pragma unroll
            for (int c = 0; c < 4; ++c) {
                int ci = c * 256 + tid;
                int row = ci >> 3;
                int sl = (ci & 7) ^ (row & 7);
                gload16(K + (size_t)(b * T + t0 + row) * D + hh * 64 + sl * 8, Ks[cur ^ 1] + (size_t)ci * 8);
                int rv = ci >> 4;
                int sv = (ci & 15) ^ (rv & 7);
                gload16(Vt + (size_t)(bh * 64 + rv) * T + t0 + sv * 8, Vs[cur ^ 1] + (size_t)ci * 8);
            }
        }
        const char* Ksc = (const char*)Ks[cur];
        const char* Vsc = (const char*)Vs[cur];

        // S^T = mfma32(K, Q) per 32-k block: lane holds S[q=q31][k=k2*32+(reg&3)+8*(reg>>2)+4h]
        f32x16 s[4];
        #pragma unroll
        for (int k2 = 0; k2 < 4; ++k2)
            #pragma unroll
            for (int e = 0; e < 16; ++e) s[k2][e] = 0.0f;
        __builtin_amdgcn_s_setprio(1);
        #pragma unroll
        for (int k2 = 0; k2 < 4; ++k2) {
            int rk = k2 * 32 + q31;
            int xm = rk & 7;
            #pragma unroll
            for (int ds = 0; ds < 4; ++ds) {
                int sp = (2 * ds + h) ^ xm;
                bf16x8 kf = *reinterpret_cast<const bf16x8*>(Ksc + rk * 128 + sp * 16);
                s[k2] = __builtin_amdgcn_mfma_f32_32x32x16_bf16(kf, qf[ds], s[k2], 0, 0, 0);
            }
        }
        __builtin_amdgcn_s_setprio(0);

        // lane-local softmax: 64 values (this lane) + partner half via 1 shfl
        float mt = -1e30f;
        #pragma unroll
        for (int k2 = 0; k2 < 4; ++k2)
            #pragma unroll
            for (int e = 0; e < 16; ++e) mt = fmaxf(mt, s[k2][e]);
        mt = fmaxf(mt, __shfl_xor(mt, 32, 64));
        bool skip = __all((int)(mt <= m_run + 11.0f));   // defer-max (T13), 2^11 headroom
        if (!skip) {
            float mn = fmaxf(m_run, mt);
            float corr = __builtin_exp2f(m_run - mn);
            m_run = mn;
            l_run *= corr;
            // redistribute corr from lane=q domain to reg-mapped O rows (16 static shfls)
            #pragma unroll
            for (int reg = 0; reg < 16; ++reg) {
                int src = ((reg & 3) + 8 * (reg >> 2)) + ((lane & 32) >> 3);
                float cr = __shfl(corr, src, 64);
                o0[reg] *= cr;
                o1[reg] *= cr;
            }
        }
        float ps0 = 0.0f, ps1 = 0.0f;
        #pragma unroll
        for (int k2 = 0; k2 < 4; ++k2)
            #pragma unroll
            for (int e = 0; e < 16; ++e) {
                float p = __builtin_exp2f(s[k2][e] - m_run);
                s[k2][e] = p;
                if (k2 & 1) ps1 += p; else ps0 += p;
            }
        float psum = ps0 + ps1;
        psum += __shfl_xor(psum, 32, 64);
        l_run += psum;

        // pack P (cvt_pk + permlane32_swap) and accumulate O += P V
        __builtin_amdgcn_s_setprio(1);
        #pragma unroll
        for (int k2 = 0; k2 < 4; ++k2) {
            u32 w0 = cvtpk(s[k2][0], s[k2][1]),   w1 = cvtpk(s[k2][2], s[k2][3]);
            u32 w2 = cvtpk(s[k2][4], s[k2][5]),   w3 = cvtpk(s[k2][6], s[k2][7]);
            u32 w4 = cvtpk(s[k2][8], s[k2][9]),   w5 = cvtpk(s[k2][10], s[k2][11]);
            u32 w6 = cvtpk(s[k2][12], s[k2][13]), w7 = cvtpk(s[k2][14], s[k2][15]);
            plswap(w0, w2); plswap(w1, w3);   // lower 16-k slice frag: [w0,w1,w2,w3]
            plswap(w4, w6); plswap(w5, w7);   // upper 16-k slice frag: [w4,w5,w6,w7]
            union { bf16x8 v; u32 u[4]; } plo, phi;
            plo.u[0] = w0; plo.u[1] = w1; plo.u[2] = w2; plo.u[3] = w3;
            phi.u[0] = w4; phi.u[1] = w5; phi.u[2] = w6; phi.u[3] = w7;
            int rv0 = q31, rv1 = 32 + q31;
            int x0 = rv0 & 7, x1 = rv1 & 7;
            int klo = 2 * k2, khi = 2 * k2 + 1;
            bf16x8 vf;
            vf = *reinterpret_cast<const bf16x8*>(Vsc + rv0 * 256 + (((2 * klo + h) ^ x0) << 4));
            o0 = __builtin_amdgcn_mfma_f32_32x32x16_bf16(plo.v, vf, o0, 0, 0, 0);
            vf = *reinterpret_cast<const bf16x8*>(Vsc + rv1 * 256 + (((2 * klo + h) ^ x1) << 4));
            o1 = __builtin_amdgcn_mfma_f32_32x32x16_bf16(plo.v, vf, o1, 0, 0, 0);
            vf = *reinterpret_cast<const bf16x8*>(Vsc + rv0 * 256 + (((2 * khi + h) ^ x0) << 4));
            o0 = __builtin_amdgcn_mfma_f32_32x32x16_bf16(phi.v, vf, o0, 0, 0, 0);
            vf = *reinterpret_cast<const bf16x8*>(Vsc + rv1 * 256 + (((2 * khi + h) ^ x1) << 4));
            o1 = __builtin_amdgcn_mfma_f32_32x32x16_bf16(phi.v, vf, o1, 0, 0, 0);
        }
        __builtin_amdgcn_s_setprio(0);
        __syncthreads();   // drains vmcnt(0): next tile staged & visible; cur buffer free
    }

    // epilogue: redistribute 1/l (lane=q domain -> reg-mapped rows), normalize, store
    float linv = 1.0f / l_run;
    #pragma unroll
    for (int reg = 0; reg < 16; ++reg) {
        int src = ((reg & 3) + 8 * (reg >> 2)) + ((lane & 32) >> 3);
        float li = __shfl(linv, src, 64);
        int qr = q0 + w * 32 + (reg & 3) + 8 * (reg >> 2) + 4 * h;
        size_t off = (size_t)(b * T + qr) * D + hh * 64 + q31;
        AO[off] = f2bf(o0[reg] * li);
        AO[off + 32] = f2bf(o1[reg] * li);
    }
}

// ---------------- output projection + bias + residual ----------------
__global__ __launch_bounds__(256, 2)
void k_ogemm(const u16* __restrict__ A, const u16* __restrict__ Wt,
             const float* __restrict__ bo, const float* __restrict__ xpe,
             float* __restrict__ y)
{
    int m0 = blockIdx.x * 128, n0 = blockIdx.y * 128;
    f32x4 acc[4][4];
    gemm128(A, Wt, m0, n0, acc);
    int lane = threadIdx.x & 63, wave = threadIdx.x >> 6;
    int wr = wave >> 1, wc = wave & 1;
    int rowbase = m0 + wr * 64 + ((lane >> 4) << 2);
    int colbase = n0 + wc * 64 + (lane & 15);
    #pragma unroll
    for (int j = 0; j < 4; ++j) {
        int c = colbase + j * 16;
        float bc = bo[c];
        #pragma unroll
        for (int i = 0; i < 4; ++i) {
            #pragma unroll
            for (int jj = 0; jj < 4; ++jj) {
                int r = rowbase + i * 16 + jj;
                y[(size_t)r * D + c] = acc[i][j][jj] + bc + xpe[(size_t)r * D + c];
            }
        }
    }
}

// ---------------- LayerNorm ----------------
__global__ __launch_bounds__(256) void k_ln(const float* __restrict__ y, const float* __restrict__ g,
                                            const float* __restrict__ bb, float* __restrict__ out)
{
    int row = blockIdx.x;
    int tid = threadIdx.x;
    const float* yr = y + (size_t)row * D;
    float4 v = *reinterpret_cast<const float4*>(yr + tid * 4);
    float s = v.x + v.y + v.z + v.w;
    float s2 = v.x * v.x + v.y * v.y + v.z * v.z + v.w * v.w;
    #pragma unroll
    for (int off = 1; off < 64; off <<= 1) {
        s += __shfl_xor(s, off, 64);
        s2 += __shfl_xor(s2, off, 64);
    }
    __shared__ float red[8];
    int wave = tid >> 6, lane = tid & 63;
    if (lane == 0) { red[wave] = s; red[4 + wave] = s2; }
    __syncthreads();
    s = red[0] + red[1] + red[2] + red[3];
    s2 = red[4] + red[5] + red[6] + red[7];
    float mu = s * (1.0f / 1024.0f);
    float var = s2 * (1.0f / 1024.0f) - mu * mu;
    float rstd = rsqrtf(var + 1e-5f);
    float4 gv = *reinterpret_cast<const float4*>(g + tid * 4);
    float4 bv = *reinterpret_cast<const float4*>(bb + tid * 4);
    float4 o;
    o.x = (v.x - mu) * rstd * gv.x + bv.x;
    o.y = (v.y - mu) * rstd * gv.y + bv.y;
    o.z = (v.z - mu) * rstd * gv.z + bv.z;
    o.w = (v.w - mu) * rstd * gv.w + bv.w;
    *reinterpret_cast<float4*>(out + (size_t)row * D + tid * 4) = o;
}

extern "C" void kernel_launch(void* const* d_in, const int* in_sizes, int n_in,
                              void* d_out, int out_size, void* d_ws, size_t ws_size,
                              hipStream_t stream)
{
    const float* x    = (const float*)d_in[0];
    const float* qtl  = (const float*)d_in[1];
    const float* qimp = (const float*)d_in[2];
    const float* Wq = (const float*)d_in[3];
    const float* bq = (const float*)d_in[4];
    const float* Wk = (const float*)d_in[5];
    const float* bk = (const float*)d_in[6];
    const float* Wv = (const float*)d_in[7];
    const float* bv = (const float*)d_in[8];
    const float* Wo = (const float*)d_in[9];
    const float* bo = (const float*)d_in[10];
    const float* qpq_w1 = (const float*)d_in[11];
    const float* qpq_b1 = (const float*)d_in[12];
    const float* qpq_w2 = (const float*)d_in[13];
    const float* qpq_b2 = (const float*)d_in[14];
    const float* qpk_w1 = (const float*)d_in[15];
    const float* qpk_b1 = (const float*)d_in[16];
    const float* qpk_w2 = (const float*)d_in[17];
    const float* qpk_b2 = (const float*)d_in[18];
    const float* qpv_w1 = (const float*)d_in[19];
    const float* qpv_b1 = (const float*)d_in[20];
    const float* qpv_w2 = (const float*)d_in[21];
    const float* qpv_b2 = (const float*)d_in[22];
    const float* ln_g = (const float*)d_in[23];
    const float* ln_b = (const float*)d_in[24];
    (void)in_sizes; (void)n_in; (void)out_size; (void)ws_size;

    char* w = (char*)d_ws;
    float* xpe   = (float*)(w);                         // 16 MB fp32 residual
    u16* xpeb    = (u16*)(w + (16u << 20));             // 8 MB bf16
    u16* Wt      = (u16*)(w + (24u << 20));             // 8 MB: Wq,Wk,Wv,Wo transposed bf16
    u16* Qb      = (u16*)(w + (32u << 20));             // 8 MB bf16 [NR][D]
    u16* Kb      = (u16*)(w + (40u << 20));             // 8 MB bf16 [NR][D]
    u16* Vtb     = (u16*)(w + (48u << 20));             // 8 MB bf16 [B*NH*64][T]
    u16* AOb     = (u16*)(w + (56u << 20));             // 8 MB bf16 [NR][D]
    float* yb    = (float*)(w + (32u << 20));           // 16 MB fp32, aliases Qb/Kb (dead then)
    float* emb   = (float*)(w + (64u << 20));           // [3][B][D]
    float* scl   = (float*)(w + (64u << 20) + 32768);   // [B]
    float* part  = (float*)(w + (64u << 20) + 65536);   // [6][4][D]

    k_mlp1<<<dim3(4, 4, 6), 256, 0, stream>>>(qtl,
        qpq_w1, qpq_b1, qpq_w2,
        qpk_w1, qpk_b1, qpk_w2,
        qpv_w1, qpv_b1, qpv_w2,
        qimp, part, scl);
    k_mlp2<<<dim3(4, 6), 256, 0, stream>>>(part, qpq_b2, qpk_b2, qpv_b2, emb);
    k_pe<<<4096, 256, 0, stream>>>(x, xpe, xpeb);
    k_wconv<<<dim3(16, 16, 4), 256, 0, stream>>>(Wq, Wk, Wv, Wo, Wt);
    k_qkv<<<dim3(32, 8, 3), 256, 0, stream>>>(xpeb, Wt, bq, bk, bv, emb, scl, Qb, Kb, Vtb);
    k_attn<<<dim3(32, 16), 256, 0, stream>>>(Qb, Kb, Vtb, AOb);
    k_ogemm<<<dim3(32, 8), 256, 0, stream>>>(AOb, Wt + (size_t)3 * D * D, bo, xpe, yb);
    k_ln<<<4096, 256, 0, stream>>>(yb, ln_g, ln_b, (float*)d_out);
}

// Round 6
// 159.909 us; speedup vs baseline: 2.4780x; 1.0158x over previous
//
#include <hip/hip_runtime.h>

#define D 1024
#define T 2048
#define BATCH 2
#define NR 4096
#define NH 16
#define HID 512

typedef unsigned short u16;
typedef unsigned int u32;
typedef unsigned long long u64;
typedef float f32x4 __attribute__((ext_vector_type(4)));
typedef float f32x16 __attribute__((ext_vector_type(16)));
typedef __bf16 bf16x8 __attribute__((ext_vector_type(8)));

// native RNE f32->bf16 (hardware v_cvt)
__device__ __forceinline__ u16 f2bf(float f) {
    union { __bf16 h; u16 u; } c; c.h = (__bf16)f; return c.u;
}

// pack two f32 -> 2xbf16 in one u32 (low = a, high = b). No builtin on gfx950 (m240).
__device__ __forceinline__ u32 cvtpk(float a, float b) {
    u32 r;
    asm("v_cvt_pk_bf16_f32 %0, %1, %2" : "=v"(r) : "v"(a), "v"(b));
    return r;
}

// v_permlane32_swap_b32: x[32..63] <-> y[0..31].
__device__ __forceinline__ void plswap(u32& x, u32& y) {
    asm volatile("v_permlane32_swap_b32 %0, %1" : "+v"(x), "+v"(y));
}

__device__ __forceinline__ float fmax3(float a, float b, float c) {
    float r; asm("v_max3_f32 %0, %1, %2, %3" : "=v"(r) : "v"(a), "v"(b), "v"(c)); return r;
}

// max over an f32x16 with ILP tree (8 ops)
__device__ __forceinline__ float vmax16(const f32x16& v) {
    float c0 = fmax3(v[0], v[1], v[2]);
    float c1 = fmax3(v[3], v[4], v[5]);
    float c2 = fmax3(v[6], v[7], v[8]);
    float c3 = fmax3(v[9], v[10], v[11]);
    c0 = fmax3(c0, v[12], v[13]);
    c1 = fmax3(c1, v[14], v[15]);
    c0 = fmax3(c0, c1, c2);
    return fmaxf(c0, c3);
}

// async global->LDS, 16B per lane. LDS dest is lane-linear; read-side XOR swizzle is
// realized by pre-swizzling the GLOBAL source column (both-sides-or-neither).
__device__ __forceinline__ void gload16(const u16* g, u16* l) {
    __builtin_amdgcn_global_load_lds(
        (const __attribute__((address_space(1))) unsigned int*)g,
        (__attribute__((address_space(3))) unsigned int*)l,
        16, 0, 0);
}

// conflict-free slot swizzle for 8-slot (128B) rows read at 32-row stride
__device__ __forceinline__ int swz8(int row) {
    return (row & 7) ^ ((row >> 3) & 3);
}

// ---------------- quantile MLP stage 1: partial sums + importance scale ----------------
__global__ __launch_bounds__(256) void k_mlp1(const float* __restrict__ qtl,
        const float* __restrict__ w1q, const float* __restrict__ b1q, const float* __restrict__ w2q,
        const float* __restrict__ w1k, const float* __restrict__ b1k, const float* __restrict__ w2k,
        const float* __restrict__ w1v, const float* __restrict__ b1v, const float* __restrict__ w2v,
        const float* __restrict__ qimp, float* __restrict__ part, float* __restrict__ scl)
{
    int dc = blockIdx.x;       // 0..3  (256 d each)
    int jc = blockIdx.y;       // 0..3  (128 j each)
    int wb = blockIdx.z;       // 0..5 : which*2 + b
    int which = wb >> 1, b = wb & 1;
    const float *w1, *b1, *w2;
    if (which == 0)      { w1 = w1q; b1 = b1q; w2 = w2q; }
    else if (which == 1) { w1 = w1k; b1 = b1k; w2 = w2k; }
    else                 { w1 = w1v; b1 = b1v; w2 = w2v; }
    int tid = threadIdx.x;
    __shared__ float h[128];
    if (tid < 128) {
        int j = jc * 128 + tid;
        h[tid] = fmaxf(qtl[b] * w1[j] + b1[j], 0.0f);
    }
    __syncthreads();
    int d = dc * 256 + tid;
    float acc = 0.0f;
    for (int j = 0; j < 128; ++j) acc += h[j] * w2[(size_t)(jc * 128 + j) * D + d];
    part[((size_t)wb * 4 + jc) * D + d] = acc;
    if (dc == 0 && jc == 0 && wb == 0 && tid < BATCH) {
        float mx = qimp[0];
        for (int i = 1; i < 100; ++i) mx = fmaxf(mx, qimp[i]);
        float q = qtl[tid];
        int idx = (int)(q * 100.0f);
        idx = idx < 0 ? 0 : (idx > 99 ? 99 : idx);
        float imp = qimp[idx];
        if (mx > 0.0f) imp /= mx;
        scl[tid] = 1.0f + imp;
    }
}

// ---------------- quantile MLP stage 2: reduce partials + bias ----------------
__global__ __launch_bounds__(256) void k_mlp2(const float* __restrict__ part,
        const float* __restrict__ b2q, const float* __restrict__ b2k, const float* __restrict__ b2v,
        float* __restrict__ embeds)
{
    int dc = blockIdx.x;   // 0..3
    int wb = blockIdx.y;   // 0..5
    int which = wb >> 1;
    const float* b2 = which == 0 ? b2q : which == 1 ? b2k : b2v;
    int d = dc * 256 + threadIdx.x;
    float acc = b2[d];
    #pragma unroll
    for (int jc = 0; jc < 4; ++jc) acc += part[((size_t)wb * 4 + jc) * D + d];
    embeds[(size_t)wb * D + d] = acc;   // [which][b][d]
}

// ---------------- x + sinusoidal PE; fp32 residual copy + bf16 copy ----------------
__global__ __launch_bounds__(256) void k_pe(const float* __restrict__ x,
                                            float* __restrict__ xpe, u16* __restrict__ xpeb)
{
    int idx = (blockIdx.x * 256 + threadIdx.x) * 4;
    int d = idx & (D - 1);
    int t = (idx >> 10) & (T - 1);
    const float KL = -0.0089944731946f;  // -ln(10000)/1024
    float ft = (float)t;
    float dv0 = __expf((float)d * KL);
    float dv1 = __expf((float)(d + 2) * KL);
    float a0 = ft * dv0, a1 = ft * dv1;
    float4 xv = *reinterpret_cast<const float4*>(x + idx);
    float4 r;
    r.x = xv.x + __sinf(a0);
    r.y = xv.y + __cosf(a0);
    r.z = xv.z + __sinf(a1);
    r.w = xv.w + __cosf(a1);
    *reinterpret_cast<float4*>(xpe + idx) = r;
    ushort4 o;
    o.x = f2bf(r.x); o.y = f2bf(r.y); o.z = f2bf(r.z); o.w = f2bf(r.w);
    *reinterpret_cast<ushort4*>(xpeb + idx) = o;
}

// ---------------- weight transpose + bf16 convert: Wt[n][k] = bf16(W[k][n]) ----------------
__global__ __launch_bounds__(256) void k_wconv(const float* __restrict__ Wq, const float* __restrict__ Wk,
                                               const float* __restrict__ Wv, const float* __restrict__ Wo,
                                               u16* __restrict__ Wt)
{
    __shared__ float tile[64][65];
    int z = blockIdx.z;
    const float* W = z == 0 ? Wq : z == 1 ? Wk : z == 2 ? Wv : Wo;
    u16* out = Wt + (size_t)z * D * D;
    int n0 = blockIdx.x * 64, k0 = blockIdx.y * 64;
    int r = threadIdx.x >> 4;
    int c4 = (threadIdx.x & 15) * 4;
    #pragma unroll
    for (int rr = 0; rr < 64; rr += 16) {
        float4 v = *reinterpret_cast<const float4*>(W + (size_t)(k0 + r + rr) * D + n0 + c4);
        tile[r + rr][c4 + 0] = v.x; tile[r + rr][c4 + 1] = v.y;
        tile[r + rr][c4 + 2] = v.z; tile[r + rr][c4 + 3] = v.w;
    }
    __syncthreads();
    #pragma unroll
    for (int rr = 0; rr < 64; rr += 16) {
        ushort4 o;
        o.x = f2bf(tile[c4 + 0][r + rr]);
        o.y = f2bf(tile[c4 + 1][r + rr]);
        o.z = f2bf(tile[c4 + 2][r + rr]);
        o.w = f2bf(tile[c4 + 3][r + rr]);
        *reinterpret_cast<ushort4*>(out + (size_t)(n0 + r + rr) * D + k0 + c4) = o;
    }
}

// ---------------- shared 128x128 bf16 MFMA GEMM core (K=1024, BK=64, m97 structure) ----------------
__device__ __forceinline__ void gemm128(const u16* __restrict__ Ag, const u16* __restrict__ Bg,
                                        int m0, int n0, f32x4 acc[4][4])
{
    __shared__ u16 As[128 * 64];
    __shared__ u16 Bs[128 * 64];
    const int tid = threadIdx.x;
    const int lane = tid & 63, wave = tid >> 6;
    const int wr = wave >> 1, wc = wave & 1;
    #pragma unroll
    for (int i = 0; i < 4; ++i)
        #pragma unroll
        for (int j = 0; j < 4; ++j)
            #pragma unroll
            for (int e = 0; e < 4; ++e) acc[i][j][e] = 0.0f;

    for (int kt = 0; kt < 16; ++kt) {
        __syncthreads();   // prev tile fully consumed by all waves
        #pragma unroll
        for (int c = 0; c < 4; ++c) {
            int ci = c * 256 + tid;
            int row = ci >> 3;
            int sl = (ci & 7) ^ (row & 7);   // pre-swizzled global column slot
            gload16(Ag + (size_t)(m0 + row) * D + kt * 64 + sl * 8, As + (size_t)ci * 8);
            gload16(Bg + (size_t)(n0 + row) * D + kt * 64 + sl * 8, Bs + (size_t)ci * 8);
        }
        __syncthreads();   // drains vmcnt(0): staged data visible to all
        #pragma unroll
        for (int ks = 0; ks < 2; ++ks) {
            bf16x8 af[4], bfr[4];
            #pragma unroll
            for (int i = 0; i < 4; ++i) {
                int ra = wr * 64 + i * 16 + (lane & 15);
                int sa = ((ks * 4 + (lane >> 4)) ^ (ra & 7));
                af[i] = *reinterpret_cast<const bf16x8*>((const char*)As + ra * 128 + sa * 16);
                int rb = wc * 64 + i * 16 + (lane & 15);
                int sb = ((ks * 4 + (lane >> 4)) ^ (rb & 7));
                bfr[i] = *reinterpret_cast<const bf16x8*>((const char*)Bs + rb * 128 + sb * 16);
            }
            #pragma unroll
            for (int i = 0; i < 4; ++i)
                #pragma unroll
                for (int j = 0; j < 4; ++j)
                    acc[i][j] = __builtin_amdgcn_mfma_f32_16x16x32_bf16(af[i], bfr[j], acc[i][j], 0, 0, 0);
        }
    }
}

// ---------------- Q/K/V projections (Q pre-scaled by scl[b]*log2(e)/sqrt(dk)) ----------------
__global__ __launch_bounds__(256, 2)
void k_qkv(const u16* __restrict__ A, const u16* __restrict__ Wt,
           const float* __restrict__ bq, const float* __restrict__ bk, const float* __restrict__ bv,
           const float* __restrict__ embeds, const float* __restrict__ scl,
           u16* __restrict__ Qo, u16* __restrict__ Ko, u16* __restrict__ Vt)
{
    int which = blockIdx.z;
    const u16* Bg = Wt + (size_t)which * D * D;
    const float* bias = which == 0 ? bq : which == 1 ? bk : bv;
    const float* emb = embeds + which * (BATCH * D);
    int m0 = blockIdx.x * 128, n0 = blockIdx.y * 128;
    f32x4 acc[4][4];
    gemm128(A, Bg, m0, n0, acc);
    int lane = threadIdx.x & 63, wave = threadIdx.x >> 6;
    int wr = wave >> 1, wc = wave & 1;
    int rowbase = m0 + wr * 64 + ((lane >> 4) << 2);
    int colbase = n0 + wc * 64 + (lane & 15);
    if (which < 2) {
        u16* Out = which == 0 ? Qo : Ko;
        float sc0 = 1.0f, sc1 = 1.0f;
        if (which == 0) {
            sc0 = scl[0] * 0.125f * 1.44269504f;   // fold 1/sqrt(dk) * temp-scale * log2(e)
            sc1 = scl[1] * 0.125f * 1.44269504f;
        }
        #pragma unroll
        for (int j = 0; j < 4; ++j) {
            int c = colbase + j * 16;
            float add0 = bias[c] + emb[c];
            float add1 = bias[c] + emb[D + c];
            #pragma unroll
            for (int i = 0; i < 4; ++i) {
                int rb = rowbase + i * 16;
                #pragma unroll
                for (int jj = 0; jj < 4; ++jj) {
                    int r = rb + jj;
                    float v = (r >> 11) ? (acc[i][j][jj] + add1) * sc1
                                        : (acc[i][j][jj] + add0) * sc0;
                    Out[(size_t)r * D + c] = f2bf(v);
                }
            }
        }
    } else {
        // V stored transposed per-head: Vt[((b*NH + h)*64 + cc)][t]
        #pragma unroll
        for (int j = 0; j < 4; ++j) {
            int c = colbase + j * 16;
            int hh = c >> 6, cc = c & 63;
            float add0 = bias[c] + emb[c];
            float add1 = bias[c] + emb[D + c];
            #pragma unroll
            for (int i = 0; i < 4; ++i) {
                int rb = rowbase + i * 16;
                int bb = rb >> 11;
                int t = rb & (T - 1);
                float add = bb ? add1 : add0;
                ushort4 o;
                o.x = f2bf(acc[i][j][0] + add);
                o.y = f2bf(acc[i][j][1] + add);
                o.z = f2bf(acc[i][j][2] + add);
                o.w = f2bf(acc[i][j][3] + add);
                *reinterpret_cast<ushort4*>(Vt + ((size_t)((bb * NH + hh) * 64 + cc)) * T + t) = o;
            }
        }
    }
}

// ---------------- flash attention: split-KV, 8 waves (2 halves x 4 q-waves), KVBLK=64 ----------------
// Each half processes kv range [half*1024, half*1024+1024) for the same 128 q rows;
// exact online-softmax merge through LDS at the end. 32x32x16 MFMA, swapped QK^T,
// in-register P (cvt_pk + permlane32_swap), conflict-free swz8 LDS swizzle.
__global__ __launch_bounds__(512, 4)
void k_attn(const u16* __restrict__ Q, const u16* __restrict__ K, const u16* __restrict__ Vt,
            u16* __restrict__ AO)
{
    __shared__ u16 Ks[2][2][64 * 64];   // [half][dbuf][t=64][d=64], 8x16B slots/row
    __shared__ u16 Vs[2][2][64 * 64];   // [half][dbuf][d=64][t=64], 8x16B slots/row
    int bh = blockIdx.x;
    int b = bh >> 4, hh = bh & 15;
    int q0 = blockIdx.y * 128;
    int tid = threadIdx.x;
    int lane = tid & 63, w = tid >> 6;
    int half = w >> 2, wq = w & 3;
    int q31 = lane & 31, h = lane >> 5;
    int sh = tid >> 8, sti = tid & 255;      // staging role: half, index-within-half
    int kvb = sh * 1024;

    // Q fragments (B-operand of mfma(K,Q))
    bf16x8 qf[4];
    {
        const u16* qp = Q + (size_t)(b * T + q0 + wq * 32 + q31) * D + hh * 64 + h * 8;
        #pragma unroll
        for (int ds = 0; ds < 4; ++ds)
            qf[ds] = *reinterpret_cast<const bf16x8*>(qp + ds * 16);
    }

    f32x16 o0, o1;
    #pragma unroll
    for (int e = 0; e < 16; ++e) { o0[e] = 0.0f; o1[e] = 0.0f; }
    float m_run = -1e30f, l_run = 0.0f;   // stats for q = q31 (log2 domain)

    // prologue: stage tile 0 of this thread's half
    #pragma unroll
    for (int c = 0; c < 2; ++c) {
        int ci = c * 256 + sti;
        int row = ci >> 3;
        int sl = (ci & 7) ^ swz8(row);
        gload16(K + (size_t)(b * T + kvb + row) * D + hh * 64 + sl * 8, Ks[sh][0] + (size_t)ci * 8);
        gload16(Vt + (size_t)(bh * 64 + row) * T + kvb + sl * 8, Vs[sh][0] + (size_t)ci * 8);
    }
    __syncthreads();

    for (int kt = 0; kt < 16; ++kt) {
        int cur = kt & 1;
        if (kt < 15) {   // issue next tile's loads under this tile's compute
            int t0 = kvb + (kt + 1) * 64;
            #pragma unroll
            for (int c = 0; c < 2; ++c) {
                int ci = c * 256 + sti;
                int row = ci >> 3;
                int sl = (ci & 7) ^ swz8(row);
                gload16(K + (size_t)(b * T + t0 + row) * D + hh * 64 + sl * 8, Ks[sh][cur ^ 1] + (size_t)ci * 8);
                gload16(Vt + (size_t)(bh * 64 + row) * T + t0 + sl * 8, Vs[sh][cur ^ 1] + (size_t)ci * 8);
            }
        }
        const char* Ksc = (const char*)Ks[half][cur];
        const char* Vsc = (const char*)Vs[half][cur];

        // S^T = mfma32(K, Q): lane holds S[q=q31][k = k2*32 + (reg&3)+8*(reg>>2)+4h]
        f32x16 s[2];
        #pragma unroll
        for (int k2 = 0; k2 < 2; ++k2)
            #pragma unroll
            for (int e = 0; e < 16; ++e) s[k2][e] = 0.0f;
        __builtin_amdgcn_s_setprio(1);
        #pragma unroll
        for (int k2 = 0; k2 < 2; ++k2) {
            int rk = k2 * 32 + q31;
            int xm = swz8(rk);
            #pragma unroll
            for (int ds = 0; ds < 4; ++ds) {
                int sp = (2 * ds + h) ^ xm;
                bf16x8 kf = *reinterpret_cast<const bf16x8*>(Ksc + rk * 128 + sp * 16);
                s[k2] = __builtin_amdgcn_mfma_f32_32x32x16_bf16(kf, qf[ds], s[k2], 0, 0, 0);
            }
        }
        __builtin_amdgcn_s_setprio(0);

        // lane-local softmax: 32 values + partner half via 1 shfl
        float mt = fmaxf(vmax16(s[0]), vmax16(s[1]));
        mt = fmaxf(mt, __shfl_xor(mt, 32, 64));
        bool skip = __all((int)(mt <= m_run + 11.0f));   // defer-max (T13)
        if (!skip) {
            float mn = fmaxf(m_run, mt);
            float corr = __builtin_exp2f(m_run - mn);
            m_run = mn;
            l_run *= corr;
            #pragma unroll
            for (int reg = 0; reg < 16; ++reg) {
                int src = ((reg & 3) + 8 * (reg >> 2)) + ((lane & 32) >> 3);
                float cr = __shfl(corr, src, 64);
                o0[reg] *= cr;
                o1[reg] *= cr;
            }
        }
        float ps0 = 0.0f, ps1 = 0.0f, ps2 = 0.0f, ps3 = 0.0f;
        #pragma unroll
        for (int k2 = 0; k2 < 2; ++k2)
            #pragma unroll
            for (int e = 0; e < 16; ++e) {
                float p = __builtin_exp2f(s[k2][e] - m_run);
                s[k2][e] = p;
                if ((e & 3) == 0) ps0 += p; else if ((e & 3) == 1) ps1 += p;
                else if ((e & 3) == 2) ps2 += p; else ps3 += p;
            }
        float psum = (ps0 + ps1) + (ps2 + ps3);
        psum += __shfl_xor(psum, 32, 64);
        l_run += psum;

        // pack P (cvt_pk + permlane32_swap) and accumulate O += P V
        __builtin_amdgcn_s_setprio(1);
        #pragma unroll
        for (int k2 = 0; k2 < 2; ++k2) {
            u32 w0 = cvtpk(s[k2][0], s[k2][1]),   w1 = cvtpk(s[k2][2], s[k2][3]);
            u32 w2 = cvtpk(s[k2][4], s[k2][5]),   w3 = cvtpk(s[k2][6], s[k2][7]);
            u32 w4 = cvtpk(s[k2][8], s[k2][9]),   w5 = cvtpk(s[k2][10], s[k2][11]);
            u32 w6 = cvtpk(s[k2][12], s[k2][13]), w7 = cvtpk(s[k2][14], s[k2][15]);
            plswap(w0, w2); plswap(w1, w3);   // t-slice 2*k2 frag
            plswap(w4, w6); plswap(w5, w7);   // t-slice 2*k2+1 frag
            union { bf16x8 v; u32 u[4]; } plo, phi;
            plo.u[0] = w0; plo.u[1] = w1; plo.u[2] = w2; plo.u[3] = w3;
            phi.u[0] = w4; phi.u[1] = w5; phi.u[2] = w6; phi.u[3] = w7;
            int rv0 = q31, rv1 = 32 + q31;
            int x0 = swz8(rv0), x1 = swz8(rv1);
            int klo = 2 * k2, khi = 2 * k2 + 1;
            bf16x8 vf;
            vf = *reinterpret_cast<const bf16x8*>(Vsc + rv0 * 128 + (((2 * klo + h) ^ x0) << 4));
            o0 = __builtin_amdgcn_mfma_f32_32x32x16_bf16(plo.v, vf, o0, 0, 0, 0);
            vf = *reinterpret_cast<const bf16x8*>(Vsc + rv1 * 128 + (((2 * klo + h) ^ x1) << 4));
            o1 = __builtin_amdgcn_mfma_f32_32x32x16_bf16(plo.v, vf, o1, 0, 0, 0);
            vf = *reinterpret_cast<const bf16x8*>(Vsc + rv0 * 128 + (((2 * khi + h) ^ x0) << 4));
            o0 = __builtin_amdgcn_mfma_f32_32x32x16_bf16(phi.v, vf, o0, 0, 0, 0);
            vf = *reinterpret_cast<const bf16x8*>(Vsc + rv1 * 128 + (((2 * khi + h) ^ x1) << 4));
            o1 = __builtin_amdgcn_mfma_f32_32x32x16_bf16(phi.v, vf, o1, 0, 0, 0);
        }
        __builtin_amdgcn_s_setprio(0);
        __syncthreads();   // drains vmcnt(0): next tile staged & visible; cur buffer free
    }

    // ---- split-KV merge through freed LDS (exact online-softmax combine) ----
    float* ML = (float*)Ks;   // [wq][2][32] : m, l per q31
    float* OB = (float*)Vs;   // [wq][row 0..31][d 0..63] partial O of half 1 (32 KB)
    if (half == 1) {
        if (h == 0) {
            ML[(wq * 2 + 0) * 32 + q31] = m_run;
            ML[(wq * 2 + 1) * 32 + q31] = l_run;
        }
        #pragma unroll
        for (int reg = 0; reg < 16; ++reg) {
            int row = (reg & 3) + 8 * (reg >> 2) + 4 * h;
            OB[((size_t)wq * 32 + row) * 64 + q31] = o0[reg];
            OB[((size_t)wq * 32 + row) * 64 + 32 + q31] = o1[reg];
        }
    }
    __syncthreads();
    if (half == 0) {
        float mB = ML[(wq * 2 + 0) * 32 + q31];
        float lB = ML[(wq * 2 + 1) * 32 + q31];
        float mn = fmaxf(m_run, mB);
        float ca = __builtin_exp2f(m_run - mn);
        float cb = __builtin_exp2f(mB - mn);
        float lf = ca * l_run + cb * lB;
        float fa = ca / lf, fb = cb / lf;
        #pragma unroll
        for (int reg = 0; reg < 16; ++reg) {
            int src = ((reg & 3) + 8 * (reg >> 2)) + ((lane & 32) >> 3);
            float far = __shfl(fa, src, 64);
            float fbr = __shfl(fb, src, 64);
            int row = (reg & 3) + 8 * (reg >> 2) + 4 * h;
            float b0 = OB[((size_t)wq * 32 + row) * 64 + q31];
            float b1 = OB[((size_t)wq * 32 + row) * 64 + 32 + q31];
            int qr = q0 + wq * 32 + row;
            size_t off = (size_t)(b * T + qr) * D + hh * 64 + q31;
            AO[off] = f2bf(o0[reg] * far + b0 * fbr);
            AO[off + 32] = f2bf(o1[reg] * far + b1 * fbr);
        }
    }
}

// ---------------- output projection + bias + residual ----------------
__global__ __launch_bounds__(256, 2)
void k_ogemm(const u16* __restrict__ A, const u16* __restrict__ Wt,
             const float* __restrict__ bo, const float* __restrict__ xpe,
             float* __restrict__ y)
{
    int m0 = blockIdx.x * 128, n0 = blockIdx.y * 128;
    f32x4 acc[4][4];
    gemm128(A, Wt, m0, n0, acc);
    int lane = threadIdx.x & 63, wave = threadIdx.x >> 6;
    int wr = wave >> 1, wc = wave & 1;
    int rowbase = m0 + wr * 64 + ((lane >> 4) << 2);
    int colbase = n0 + wc * 64 + (lane & 15);
    #pragma unroll
    for (int j = 0; j < 4; ++j) {
        int c = colbase + j * 16;
        float bc = bo[c];
        #pragma unroll
        for (int i = 0; i < 4; ++i) {
            #pragma unroll
            for (int jj = 0; jj < 4; ++jj) {
                int r = rowbase + i * 16 + jj;
                y[(size_t)r * D + c] = acc[i][j][jj] + bc + xpe[(size_t)r * D + c];
            }
        }
    }
}

// ---------------- LayerNorm ----------------
__global__ __launch_bounds__(256) void k_ln(const float* __restrict__ y, const float* __restrict__ g,
                                            const float* __restrict__ bb, float* __restrict__ out)
{
    int row = blockIdx.x;
    int tid = threadIdx.x;
    const float* yr = y + (size_t)row * D;
    float4 v = *reinterpret_cast<const float4*>(yr + tid * 4);
    float s = v.x + v.y + v.z + v.w;
    float s2 = v.x * v.x + v.y * v.y + v.z * v.z + v.w * v.w;
    #pragma unroll
    for (int off = 1; off < 64; off <<= 1) {
        s += __shfl_xor(s, off, 64);
        s2 += __shfl_xor(s2, off, 64);
    }
    __shared__ float red[8];
    int wave = tid >> 6, lane = tid & 63;
    if (lane == 0) { red[wave] = s; red[4 + wave] = s2; }
    __syncthreads();
    s = red[0] + red[1] + red[2] + red[3];
    s2 = red[4] + red[5] + red[6] + red[7];
    float mu = s * (1.0f / 1024.0f);
    float var = s2 * (1.0f / 1024.0f) - mu * mu;
    float rstd = rsqrtf(var + 1e-5f);
    float4 gv = *reinterpret_cast<const float4*>(g + tid * 4);
    float4 bv = *reinterpret_cast<const float4*>(bb + tid * 4);
    float4 o;
    o.x = (v.x - mu) * rstd * gv.x + bv.x;
    o.y = (v.y - mu) * rstd * gv.y + bv.y;
    o.z = (v.z - mu) * rstd * gv.z + bv.z;
    o.w = (v.w - mu) * rstd * gv.w + bv.w;
    *reinterpret_cast<float4*>(out + (size_t)row * D + tid * 4) = o;
}

extern "C" void kernel_launch(void* const* d_in, const int* in_sizes, int n_in,
                              void* d_out, int out_size, void* d_ws, size_t ws_size,
                              hipStream_t stream)
{
    const float* x    = (const float*)d_in[0];
    const float* qtl  = (const float*)d_in[1];
    const float* qimp = (const float*)d_in[2];
    const float* Wq = (const float*)d_in[3];
    const float* bq = (const float*)d_in[4];
    const float* Wk = (const float*)d_in[5];
    const float* bk = (const float*)d_in[6];
    const float* Wv = (const float*)d_in[7];
    const float* bv = (const float*)d_in[8];
    const float* Wo = (const float*)d_in[9];
    const float* bo = (const float*)d_in[10];
    const float* qpq_w1 = (const float*)d_in[11];
    const float* qpq_b1 = (const float*)d_in[12];
    const float* qpq_w2 = (const float*)d_in[13];
    const float* qpq_b2 = (const float*)d_in[14];
    const float* qpk_w1 = (const float*)d_in[15];
    const float* qpk_b1 = (const float*)d_in[16];
    const float* qpk_w2 = (const float*)d_in[17];
    const float* qpk_b2 = (const float*)d_in[18];
    const float* qpv_w1 = (const float*)d_in[19];
    const float* qpv_b1 = (const float*)d_in[20];
    const float* qpv_w2 = (const float*)d_in[21];
    const float* qpv_b2 = (const float*)d_in[22];
    const float* ln_g = (const float*)d_in[23];
    const float* ln_b = (const float*)d_in[24];
    (void)in_sizes; (void)n_in; (void)out_size; (void)ws_size;

    char* w = (char*)d_ws;
    float* xpe   = (float*)(w);                         // 16 MB fp32 residual
    u16* xpeb    = (u16*)(w + (16u << 20));             // 8 MB bf16
    u16* Wt      = (u16*)(w + (24u << 20));             // 8 MB: Wq,Wk,Wv,Wo transposed bf16
    u16* Qb      = (u16*)(w + (32u << 20));             // 8 MB bf16 [NR][D]
    u16* Kb      = (u16*)(w + (40u << 20));             // 8 MB bf16 [NR][D]
    u16* Vtb     = (u16*)(w + (48u << 20));             // 8 MB bf16 [B*NH*64][T]
    u16* AOb     = (u16*)(w + (56u << 20));             // 8 MB bf16 [NR][D]
    float* yb    = (float*)(w + (32u << 20));           // 16 MB fp32, aliases Qb/Kb (dead then)
    float* emb   = (float*)(w + (64u << 20));           // [3][B][D]
    float* scl   = (float*)(w + (64u << 20) + 32768);   // [B]
    float* part  = (float*)(w + (64u << 20) + 65536);   // [6][4][D]

    k_mlp1<<<dim3(4, 4, 6), 256, 0, stream>>>(qtl,
        qpq_w1, qpq_b1, qpq_w2,
        qpk_w1, qpk_b1, qpk_w2,
        qpv_w1, qpv_b1, qpv_w2,
        qimp, part, scl);
    k_mlp2<<<dim3(4, 6), 256, 0, stream>>>(part, qpq_b2, qpk_b2, qpv_b2, emb);
    k_pe<<<4096, 256, 0, stream>>>(x, xpe, xpeb);
    k_wconv<<<dim3(16, 16, 4), 256, 0, stream>>>(Wq, Wk, Wv, Wo, Wt);
    k_qkv<<<dim3(32, 8, 3), 256, 0, stream>>>(xpeb, Wt, bq, bk, bv, emb, scl, Qb, Kb, Vtb);
    k_attn<<<dim3(32, 16), 512, 0, stream>>>(Qb, Kb, Vtb, AOb);
    k_ogemm<<<dim3(32, 8), 256, 0, stream>>>(AOb, Wt + (size_t)3 * D * D, bo, xpe, yb);
    k_ln<<<4096, 256, 0, stream>>>(yb, ln_g, ln_b, (float*)d_out);
}